// Round 3
// baseline (1279.561 us; speedup 1.0000x reference)
//
#include <hip/hip_runtime.h>
#include <math.h>

#define NN 50000
#define NE 1000000
#define NG 256
#define ORIGD 92
#define NBRD 41
#define NSPREAD 32
#define SCAN_B 256

typedef unsigned short u16;
typedef __attribute__((ext_vector_type(8))) short short8;   // 8 x bf16 MFMA frag
typedef __attribute__((ext_vector_type(4))) float f32x4;    // MFMA accumulator
typedef __attribute__((ext_vector_type(8))) float f32x8;    // packed P chunk

// ---- workspace layout (float offsets) ----
#define OFF_AFB     0                        // 50000*64 bf16
#define OFF_SUMMED  1600000                  // 50000*64 fp32
#define OFF_WT      4800000                  // t2: 128x192 bf16 | t3/t4: wT3 128x64 + wP 256x64
#define OFF_BN1SPR  4812288                  // 32*256
#define OFF_BN1SC   4820480                  // 256 (fallback paths only)
#define OFF_BN2ACC  4820736                  // 128
#define OFF_BN2SC   4820864                  // 128 (fallback paths only)
#define OFF_ELOG    4820992                  // 50000
#define OFF_SEGMAX  4870992                  // 256
#define OFF_DENOM   4871248                  // 256
#define OFF_CNT     4871504                  // 50000 int
#define OFF_PTR     4921504                  // 50000 int
#define OFF_HEAD    4971504                  // 50000 int
#define OFF_BSUM    5021504                  // 256 int (fallback)
#define OFF_BOFS    5021760                  // 256 int (fallback)
#define OFF_EIDX    5022016                  // 1M int (fallback t3/t2)
#define OFF_H       6022016                  // 1M*128 bf16 (256 MB)
#define OFF_T2_END  70022016
#define OFF_P       70022016                 // t3/t4: 50000*256 fp32 node pre-proj
#define OFF_T3_END  82822016
#define OFF_SRCC    82822016                 // t4: 1M int src in CSR order
#define OFF_DSTC    83822016                 // t4: 1M int dst in CSR order
#define OFF_EAB     84822016                 // t4: 1M*48 bf16 edge_attr (CSR order)
#define OFF_T4_END  108822016

__device__ __forceinline__ u16 f2b(float f) {          // fp32 -> bf16 RNE
    unsigned u = __float_as_uint(f);
    return (u16)((u + 0x7FFFu + ((u >> 16) & 1u)) >> 16);
}
__device__ __forceinline__ float b2f(u16 u) {
    return __uint_as_float(((unsigned)u) << 16);
}
__device__ __forceinline__ float gate(float f, float cc) {
    float sig = __builtin_amdgcn_rcpf(1.f + __expf(-f));
    float sp  = fmaxf(cc, 0.f) + __logf(1.f + __expf(-fabsf(cc)));
    return sig * sp;
}
__device__ __forceinline__ float fsilu(float x) {
    return x * __builtin_amdgcn_rcpf(1.f + __expf(-x));
}

// ---------------- t4 mega-prolog: embed + weight prep + workspace zeroing ------
// zero region A = [BN1SPR, ELOG) 8704 words; region B = [SEGMAX, CNT+50000) 50512 words
__global__ __launch_bounds__(256) void k_embed2(
    const float* __restrict__ x, const float* __restrict__ lf,
    const float* __restrict__ W, const float* __restrict__ b,
    u16* __restrict__ afb, const float* __restrict__ fcW,
    u16* __restrict__ wT3, u16* __restrict__ wP, float* __restrict__ ws)
{
    int gid = blockIdx.x * 256 + threadIdx.x;
    int n = gid >> 6, c = gid & 63;
    const float* xr = x + (long)n * ORIGD;
    float acc = b[c] + lf[gid];
#pragma unroll 4
    for (int k = 0; k < ORIGD; k++)
        acc = fmaf(xr[k], W[k * 64 + c], acc);
    afb[gid] = f2b(acc);

    if (blockIdx.x < 96) {                      // prepw2 work
        int i = blockIdx.x * 256 + threadIdx.x; // 24576 = 8192 + 16384
        if (i < 8192) {
            int j = i >> 6, k = i & 63;
            wT3[i] = (k < NBRD) ? f2b(fcW[(128 + k) * 128 + j]) : (u16)0;
        } else {
            int i2 = i - 8192;
            int j = i2 >> 6, k = i2 & 63;
            int row = (j < 128) ? k : (64 + k);
            wP[i2] = f2b(fcW[row * 128 + (j & 127)]);
        }
    } else if (blockIdx.x < 336) {              // zeroing work
        int zid = (blockIdx.x - 96) * 256 + threadIdx.x;
        if (zid < 8704) {
            ws[OFF_BN1SPR + zid] = 0.f;
        } else {
            int z2 = zid - 8704;
            if (z2 < 50512) ws[OFF_SEGMAX + z2] = 0.f;
        }
    }
}

// ---------------- prep (t2 path) ----
__global__ void k_prepw(const float* __restrict__ fcW, u16* __restrict__ wT)
{
    int i = blockIdx.x * 256 + threadIdx.x;        // 24576
    int j = i / 192, k = i - j * 192;
    wT[i] = (k < 169) ? f2b(fcW[k * 128 + j]) : (u16)0;
}

// ---------------- prep (t3 fallback) ----
__global__ void k_prepw2(const float* __restrict__ fcW, u16* __restrict__ wT3,
                         u16* __restrict__ wP)
{
    int i = blockIdx.x * 256 + threadIdx.x;
    if (i < 8192) {
        int j = i >> 6, k = i & 63;
        wT3[i] = (k < NBRD) ? f2b(fcW[(128 + k) * 128 + j]) : (u16)0;
    } else {
        int i2 = i - 8192;
        int j = i2 >> 6, k = i2 & 63;
        int row = (j < 128) ? k : (64 + k);
        wP[i2] = f2b(fcW[row * 128 + (j & 127)]);
    }
}

// ---------------- t2 fallback embed ----
__global__ __launch_bounds__(256) void k_embed(
    const float* __restrict__ x, const float* __restrict__ lf,
    const float* __restrict__ W, const float* __restrict__ b,
    u16* __restrict__ afb)
{
    int gid = blockIdx.x * 256 + threadIdx.x;
    int n = gid >> 6, c = gid & 63;
    const float* xr = x + (long)n * ORIGD;
    float acc = b[c] + lf[gid];
#pragma unroll 4
    for (int k = 0; k < ORIGD; k++)
        acc = fmaf(xr[k], W[k * 64 + c], acc);
    afb[gid] = f2b(acc);
}

// ---------------- node pre-projection --------------------------------------
// PACKED=1 (t4): P[n][jp] with jp grouping each (w,quad) lane's 8 channels
// {j0..j0+3, 64+j0..64+j0+3} into one contiguous 32B chunk; halves 0/128 = P1/P2.
// PACKED=0 (t3): plain column order.
template <int PACKED>
__global__ __launch_bounds__(256) void k_pnode(
    const u16* __restrict__ afb, const u16* __restrict__ wP, float* __restrict__ P)
{
    __shared__ __align__(16) u16 sB[64 * 72];
    const int tid = threadIdx.x;
    const int n0 = blockIdx.x * 64;

    for (int i = tid; i < 512; i += 256) {
        int r = i >> 3, c = i & 7;
        int n = n0 + r;
        short8 v = {0,0,0,0,0,0,0,0};
        if (n < NN) v = *(const short8*)(afb + (long)n * 64 + c * 8);
        *(short8*)(sB + r * 72 + c * 8) = v;
    }
    __syncthreads();

    const int lane = tid & 63, w = tid >> 6;
    const int n16 = lane & 15, quad = lane >> 4;
    short8 A[4][2];
#pragma unroll
    for (int m = 0; m < 4; m++) {
        const u16* base = wP + (16 * (w + 4 * m) + n16) * 64 + quad * 8;
        A[m][0] = *(const short8*)(base);
        A[m][1] = *(const short8*)(base + 32);
    }
    for (int t = 0; t < 4; t++) {
        const u16* row = sB + (16 * t + n16) * 72 + quad * 8;
        short8 b0 = *(const short8*)(row);
        short8 b1 = *(const short8*)(row + 32);
        int n = n0 + 16 * t + n16;
#pragma unroll
        for (int m = 0; m < 4; m++) {
            f32x4 acc = {0.f, 0.f, 0.f, 0.f};
            acc = __builtin_amdgcn_mfma_f32_16x16x32_bf16(A[m][0], b0, acc, 0, 0, 0);
            acc = __builtin_amdgcn_mfma_f32_16x16x32_bf16(A[m][1], b1, acc, 0, 0, 0);
            if (n < NN) {
                int M = w + 4 * m;
                int j;
                if (PACKED) {
                    int MM = M & 7;
                    j = ((M >> 3) * 128) + ((MM & 3) * 4 + quad) * 8 + ((MM >> 2) << 2);
                } else {
                    j = 16 * M + 4 * quad;
                }
                *(f32x4*)(P + (long)n * 256 + j) = acc;
            }
        }
    }
}

// ---------------- CSR build ----------------
__global__ void k_hist(const int* __restrict__ ei, int* __restrict__ cnt)
{
    int e = blockIdx.x * 256 + threadIdx.x;
    if (e < NE) atomicAdd(&cnt[ei[e]], 1);
}

// t4: whole exclusive scan in ONE block (NN=50000, 1024 threads x 49 chunk)
__global__ __launch_bounds__(1024) void k_scan1b(const int* __restrict__ cnt,
                                                 int* __restrict__ ptr,
                                                 int* __restrict__ head)
{
    __shared__ int sw[16];
    const int t = threadIdx.x;
    const int CH = (NN + 1023) / 1024;          // 49
    const int base = t * CH;
    int s = 0;
    for (int i = 0; i < CH; i++) {
        int n = base + i;
        s += (n < NN) ? cnt[n] : 0;
    }
    int lane = t & 63, wv = t >> 6;
    int v = s;
    for (int o = 1; o < 64; o <<= 1) {
        int x = __shfl_up(v, o, 64);
        if (lane >= o) v += x;
    }
    if (lane == 63) sw[wv] = v;
    __syncthreads();
    if (t == 0) {
        int acc = 0;
        for (int i = 0; i < 16; i++) { int x = sw[i]; sw[i] = acc; acc += x; }
    }
    __syncthreads();
    int p = sw[wv] + (v - s);                   // exclusive prefix for this thread
    for (int i = 0; i < CH; i++) {
        int n = base + i;
        if (n < NN) { ptr[n] = p; head[n] = p; p += cnt[n]; }
    }
}

// fallback scan kernels (t3/t2)
__global__ void k_partial(const int* __restrict__ cnt, int* __restrict__ lofs,
                          int* __restrict__ bsum)
{
    __shared__ int sd[SCAN_B];
    int t = threadIdx.x, b = blockIdx.x, n = b * SCAN_B + t;
    int v = (n < NN) ? cnt[n] : 0;
    sd[t] = v; __syncthreads();
    for (int o = 1; o < SCAN_B; o <<= 1) {
        int x = (t >= o) ? sd[t - o] : 0;
        __syncthreads();
        sd[t] += x;
        __syncthreads();
    }
    if (n < NN) lofs[n] = sd[t] - v;
    if (t == SCAN_B - 1) bsum[b] = sd[t];
}

__global__ void k_scanb(const int* __restrict__ bsum, int* __restrict__ bofs, int nb)
{
    __shared__ int sd[256];
    int t = threadIdx.x;
    int v = (t < nb) ? bsum[t] : 0;
    sd[t] = v; __syncthreads();
    for (int o = 1; o < 256; o <<= 1) {
        int x = (t >= o) ? sd[t - o] : 0;
        __syncthreads();
        sd[t] += x;
        __syncthreads();
    }
    bofs[t] = sd[t] - v;
}

__global__ void k_addofs(int* __restrict__ ptr, const int* __restrict__ bofs,
                         int* __restrict__ head)
{
    int n = blockIdx.x * 256 + threadIdx.x;
    if (n < NN) {
        int p = ptr[n] + bofs[n >> 8];
        ptr[n] = p; head[n] = p;
    }
}

__global__ void k_fill(const int* __restrict__ ei, int* __restrict__ head,
                       int* __restrict__ eidx)
{
    int e = blockIdx.x * 256 + threadIdx.x;
    if (e < NE) {
        int pos = atomicAdd(&head[ei[e]], 1);
        eidx[pos] = e;
    }
}

// t4: CSR fill fused with edge_attr gather->bf16 pad at CSR position
__global__ __launch_bounds__(256) void k_fill3(
    const int* __restrict__ ei, const float* __restrict__ ea,
    int* __restrict__ head, int* __restrict__ srcC, int* __restrict__ dstC,
    u16* __restrict__ eaB)
{
    int e = blockIdx.x * 256 + threadIdx.x;
    if (e >= NE) return;
    int s = ei[e];
    int pos = atomicAdd(&head[s], 1);
    srcC[pos] = s;
    dstC[pos] = ei[NE + e];
    const float* row = ea + (long)e * NBRD;
    u16* orow = eaB + (long)pos * 48;
#pragma unroll
    for (int q = 0; q < 6; q++) {
        short8 v;
#pragma unroll
        for (int j = 0; j < 8; j++) {
            int c = q * 8 + j;
            v[j] = (c < NBRD) ? (short)f2b(row[c]) : (short)0;
        }
        *(short8*)(orow + q * 8) = v;
    }
}

// ---------------- t4 edge pass: CSR order, packed-P, sequential eaB ------------
__global__ __launch_bounds__(256) void k_gemm_h4(
    const u16* __restrict__ eaB, const int* __restrict__ srcC,
    const int* __restrict__ dstC, const u16* __restrict__ wT3,
    const float* __restrict__ P, u16* __restrict__ h,
    float* __restrict__ spread)
{
    const int tid = threadIdx.x;
    const int e0 = blockIdx.x * 64;
    const int lane = tid & 63, w = tid >> 6;
    const int n16 = lane & 15, quad = lane >> 4;

    short8 A0[2], A1[2];
    {
        const u16* a0 = wT3 + (16 * w + n16) * 64 + quad * 8;
        const u16* a1 = wT3 + (16 * (w + 4) + n16) * 64 + quad * 8;
        A0[0] = *(const short8*)(a0);  A0[1] = *(const short8*)(a0 + 32);
        A1[0] = *(const short8*)(a1);  A1[1] = *(const short8*)(a1 + 32);
    }

    const int j0 = 16 * w + 4 * quad;
    const int pofs = (w * 4 + quad) * 8;
    const short8 bz = {0,0,0,0,0,0,0,0};
    float s0[4] = {0,0,0,0}, q0[4] = {0,0,0,0}, s1[4] = {0,0,0,0}, q1[4] = {0,0,0,0};

#pragma unroll
    for (int t = 0; t < 4; t++) {
        const int pos = e0 + 16 * t + n16;
        const int src = srcC[pos];
        const int dst = dstC[pos];

        // edge_attr fragments: fully sequential (CSR-ordered eaB)
        const u16* er = eaB + (long)pos * 48;
        short8 b0 = *(const short8*)(er + quad * 8);
        short8 b1 = bz;
        if (quad < 2) b1 = *(const short8*)(er + 32 + quad * 8);

        // node contributions: one 32B chunk per side (1 line P2, P1 L1-hot)
        f32x8 gS = *(const f32x8*)(P + (long)src * 256 + pofs);
        f32x8 gD = *(const f32x8*)(P + (long)dst * 256 + 128 + pofs);

        f32x4 acc0 = {0.f, 0.f, 0.f, 0.f}, acc1 = {0.f, 0.f, 0.f, 0.f};
        acc0 = __builtin_amdgcn_mfma_f32_16x16x32_bf16(A0[0], b0, acc0, 0, 0, 0);
        acc0 = __builtin_amdgcn_mfma_f32_16x16x32_bf16(A0[1], b1, acc0, 0, 0, 0);
        acc1 = __builtin_amdgcn_mfma_f32_16x16x32_bf16(A1[0], b0, acc1, 0, 0, 0);
        acc1 = __builtin_amdgcn_mfma_f32_16x16x32_bf16(A1[1], b1, acc1, 0, 0, 0);

        u16 hv0[4], hv1[4];
#pragma unroll
        for (int r = 0; r < 4; r++) {
            float u0 = acc0[r] + gS[r] + gD[r];
            float u1 = acc1[r] + gS[4 + r] + gD[4 + r];
            s0[r] += u0; q0[r] = fmaf(u0, u0, q0[r]);
            s1[r] += u1; q1[r] = fmaf(u1, u1, q1[r]);
            hv0[r] = f2b(u0); hv1[r] = f2b(u1);
        }
        u16* hp = h + (long)pos * 128 + j0;
        ushort4 v0 = make_ushort4(hv0[0], hv0[1], hv0[2], hv0[3]);
        ushort4 v1 = make_ushort4(hv1[0], hv1[1], hv1[2], hv1[3]);
        *(ushort4*)hp = v0;
        *(ushort4*)(hp + 64) = v1;
    }

#pragma unroll
    for (int m = 1; m < 16; m <<= 1) {
#pragma unroll
        for (int r = 0; r < 4; r++) {
            s0[r] += __shfl_xor(s0[r], m); q0[r] += __shfl_xor(q0[r], m);
            s1[r] += __shfl_xor(s1[r], m); q1[r] += __shfl_xor(q1[r], m);
        }
    }
    if (n16 == 0) {
        float* sp = spread + (blockIdx.x & (NSPREAD - 1)) * 256;
#pragma unroll
        for (int r = 0; r < 4; r++) {
            atomicAdd(sp + j0 + r,       s0[r]);
            atomicAdd(sp + 128 + j0 + r, q0[r]);
            atomicAdd(sp + 64 + j0 + r,  s1[r]);
            atomicAdd(sp + 192 + j0 + r, q1[r]);
        }
    }
}

// ---------------- t3 edge pass (fallback) -------------------------------------
__global__ __launch_bounds__(256) void k_gemm_h2(
    const float* __restrict__ ea, const int* __restrict__ ei,
    const u16* __restrict__ wT3, const float* __restrict__ P,
    u16* __restrict__ h, float* __restrict__ spread)
{
    __shared__ __align__(16) u16 sTl[64 * 72];
    __shared__ int sSrc[64], sDst[64];
    const int tid = threadIdx.x;
    const int e0 = blockIdx.x * 64;

    if (tid < 64) sSrc[tid] = ei[e0 + tid];
    else if (tid < 128) sDst[tid - 64] = ei[NE + e0 + tid - 64];

    for (int i = tid; i < 64 * 64; i += 256) {
        int e = i >> 6, c = i & 63;
        float v = (c < NBRD) ? ea[(long)(e0 + e) * NBRD + c] : 0.f;
        sTl[e * 72 + c] = f2b(v);
    }
    __syncthreads();

    const int lane = tid & 63, w = tid >> 6;
    const int n16 = lane & 15, quad = lane >> 4;

    short8 A0[2], A1[2];
    {
        const u16* b0 = wT3 + (16 * w + n16) * 64 + quad * 8;
        const u16* b1 = wT3 + (16 * (w + 4) + n16) * 64 + quad * 8;
        A0[0] = *(const short8*)(b0);  A0[1] = *(const short8*)(b0 + 32);
        A1[0] = *(const short8*)(b1);  A1[1] = *(const short8*)(b1 + 32);
    }

    const int j0 = 16 * w + 4 * quad;
    float s0[4] = {0,0,0,0}, q0[4] = {0,0,0,0}, s1[4] = {0,0,0,0}, q1[4] = {0,0,0,0};

    for (int t = 0; t < 4; t++) {
        const int ge16 = 16 * t + n16;
        const int src = sSrc[ge16], dst = sDst[ge16];
        const float* pS = P + (long)src * 256;
        const float* pD = P + (long)dst * 256 + 128;
        f32x4 g0 = *(const f32x4*)(pS + j0);
        f32x4 g1 = *(const f32x4*)(pS + 64 + j0);
        f32x4 g2 = *(const f32x4*)(pD + j0);
        f32x4 g3 = *(const f32x4*)(pD + 64 + j0);

        const u16* row = sTl + ge16 * 72 + quad * 8;
        short8 b0 = *(const short8*)(row);
        short8 b1 = *(const short8*)(row + 32);
        f32x4 acc0 = {0.f, 0.f, 0.f, 0.f}, acc1 = {0.f, 0.f, 0.f, 0.f};
        acc0 = __builtin_amdgcn_mfma_f32_16x16x32_bf16(A0[0], b0, acc0, 0, 0, 0);
        acc0 = __builtin_amdgcn_mfma_f32_16x16x32_bf16(A0[1], b1, acc0, 0, 0, 0);
        acc1 = __builtin_amdgcn_mfma_f32_16x16x32_bf16(A1[0], b0, acc1, 0, 0, 0);
        acc1 = __builtin_amdgcn_mfma_f32_16x16x32_bf16(A1[1], b1, acc1, 0, 0, 0);

        u16 hv0[4], hv1[4];
#pragma unroll
        for (int r = 0; r < 4; r++) {
            float u0 = acc0[r] + g0[r] + g2[r];
            float u1 = acc1[r] + g1[r] + g3[r];
            s0[r] += u0; q0[r] = fmaf(u0, u0, q0[r]);
            s1[r] += u1; q1[r] = fmaf(u1, u1, q1[r]);
            hv0[r] = f2b(u0); hv1[r] = f2b(u1);
        }
        int ge = e0 + ge16;
        u16* hp = h + (long)ge * 128 + j0;
        ushort4 v0 = make_ushort4(hv0[0], hv0[1], hv0[2], hv0[3]);
        ushort4 v1 = make_ushort4(hv1[0], hv1[1], hv1[2], hv1[3]);
        *(ushort4*)hp = v0;
        *(ushort4*)(hp + 64) = v1;
    }

#pragma unroll
    for (int m = 1; m < 16; m <<= 1) {
#pragma unroll
        for (int r = 0; r < 4; r++) {
            s0[r] += __shfl_xor(s0[r], m); q0[r] += __shfl_xor(q0[r], m);
            s1[r] += __shfl_xor(s1[r], m); q1[r] += __shfl_xor(q1[r], m);
        }
    }
    if (n16 == 0) {
        float* sp = spread + (blockIdx.x & (NSPREAD - 1)) * 256;
#pragma unroll
        for (int r = 0; r < 4; r++) {
            atomicAdd(sp + j0 + r,       s0[r]);
            atomicAdd(sp + 128 + j0 + r, q0[r]);
            atomicAdd(sp + 64 + j0 + r,  s1[r]);
            atomicAdd(sp + 192 + j0 + r, q1[r]);
        }
    }
}

// ---------------- t2 fused GEMM pass (fallback) --------------------------------
__global__ __launch_bounds__(256) void k_gemm_h(
    const u16* __restrict__ afb, const float* __restrict__ ea,
    const int* __restrict__ ei, const u16* __restrict__ wT,
    u16* __restrict__ h, float* __restrict__ spread)
{
    __shared__ __align__(16) u16 sTl[64 * 200];
    __shared__ int sSrc[64], sDst[64];
    const int tid = threadIdx.x;
    const int e0 = blockIdx.x * 64;

    if (tid < 64) sSrc[tid] = ei[e0 + tid];
    else if (tid < 128) sDst[tid - 64] = ei[NE + e0 + tid - 64];
    __syncthreads();

    for (int i = tid; i < 1024; i += 256) {
        int e = i >> 4, q = i & 15;
        const u16* g = (q < 8) ? (afb + (long)sSrc[e] * 64 + q * 8)
                               : (afb + (long)sDst[e] * 64 + (q - 8) * 8);
        *(short8*)(sTl + e * 200 + q * 8) = *(const short8*)g;
    }
    for (int i = tid; i < 64 * 64; i += 256) {
        int e = i >> 6, c = i & 63;
        float v = (c < NBRD) ? ea[(long)(e0 + e) * NBRD + c] : 0.f;
        sTl[e * 200 + 128 + c] = f2b(v);
    }
    __syncthreads();

    const int lane = tid & 63, w = tid >> 6;
    const int n16 = lane & 15, quad = lane >> 4;

    short8 A0[6], A1[6];
    {
        const u16* b0 = wT + (16 * w + n16) * 192 + quad * 8;
        const u16* b1 = wT + (16 * (w + 4) + n16) * 192 + quad * 8;
#pragma unroll
        for (int ks = 0; ks < 6; ks++) {
            A0[ks] = *(const short8*)(b0 + ks * 32);
            A1[ks] = *(const short8*)(b1 + ks * 32);
        }
    }

    const int j0 = 16 * w + 4 * quad;
    float s0[4] = {0,0,0,0}, q0[4] = {0,0,0,0}, s1[4] = {0,0,0,0}, q1[4] = {0,0,0,0};

    for (int t = 0; t < 4; t++) {
        const u16* row = sTl + (16 * t + n16) * 200 + quad * 8;
        f32x4 acc0 = {0.f, 0.f, 0.f, 0.f}, acc1 = {0.f, 0.f, 0.f, 0.f};
#pragma unroll
        for (int ks = 0; ks < 6; ks++) {
            short8 b = *(const short8*)(row + ks * 32);
            acc0 = __builtin_amdgcn_mfma_f32_16x16x32_bf16(A0[ks], b, acc0, 0, 0, 0);
            acc1 = __builtin_amdgcn_mfma_f32_16x16x32_bf16(A1[ks], b, acc1, 0, 0, 0);
        }
#pragma unroll
        for (int r = 0; r < 4; r++) {
            s0[r] += acc0[r]; q0[r] = fmaf(acc0[r], acc0[r], q0[r]);
            s1[r] += acc1[r]; q1[r] = fmaf(acc1[r], acc1[r], q1[r]);
        }
        int ge = e0 + 16 * t + n16;
        u16* hp = h + (long)ge * 128 + j0;
        ushort4 v0 = make_ushort4(f2b(acc0[0]), f2b(acc0[1]), f2b(acc0[2]), f2b(acc0[3]));
        ushort4 v1 = make_ushort4(f2b(acc1[0]), f2b(acc1[1]), f2b(acc1[2]), f2b(acc1[3]));
        *(ushort4*)hp = v0;
        *(ushort4*)(hp + 64) = v1;
    }

#pragma unroll
    for (int m = 1; m < 16; m <<= 1) {
#pragma unroll
        for (int r = 0; r < 4; r++) {
            s0[r] += __shfl_xor(s0[r], m); q0[r] += __shfl_xor(q0[r], m);
            s1[r] += __shfl_xor(s1[r], m); q1[r] += __shfl_xor(q1[r], m);
        }
    }
    if (n16 == 0) {
        float* sp = spread + (blockIdx.x & (NSPREAD - 1)) * 256;
#pragma unroll
        for (int r = 0; r < 4; r++) {
            atomicAdd(sp + j0 + r,       s0[r]);
            atomicAdd(sp + 128 + j0 + r, q0[r]);
            atomicAdd(sp + 64 + j0 + r,  s1[r]);
            atomicAdd(sp + 192 + j0 + r, q1[r]);
        }
    }
}

// ---------------- fallback two-pass GEMM (tiny ws) ----------------------------
template <int MODE>
__global__ __launch_bounds__(256) void k_gemm(
    const u16* __restrict__ afb, const float* __restrict__ ea,
    const int* __restrict__ ei, const u16* __restrict__ wT,
    const float* __restrict__ sc, float* __restrict__ outbuf)
{
    __shared__ __align__(16) u16 sTl[64 * 200];
    __shared__ int sSrc[64], sDst[64];
    const int tid = threadIdx.x;
    const int e0 = blockIdx.x * 64;

    if (tid < 64) sSrc[tid] = ei[e0 + tid];
    else if (tid < 128) sDst[tid - 64] = ei[NE + e0 + tid - 64];
    __syncthreads();
    for (int i = tid; i < 1024; i += 256) {
        int e = i >> 4, q = i & 15;
        const u16* g = (q < 8) ? (afb + (long)sSrc[e] * 64 + q * 8)
                               : (afb + (long)sDst[e] * 64 + (q - 8) * 8);
        *(short8*)(sTl + e * 200 + q * 8) = *(const short8*)g;
    }
    for (int i = tid; i < 64 * 64; i += 256) {
        int e = i >> 6, c = i & 63;
        float v = (c < NBRD) ? ea[(long)(e0 + e) * NBRD + c] : 0.f;
        sTl[e * 200 + 128 + c] = f2b(v);
    }
    __syncthreads();

    const int lane = tid & 63, w = tid >> 6;
    const int n16 = lane & 15, quad = lane >> 4;
    short8 A0[6], A1[6];
    {
        const u16* b0 = wT + (16 * w + n16) * 192 + quad * 8;
        const u16* b1 = wT + (16 * (w + 4) + n16) * 192 + quad * 8;
#pragma unroll
        for (int ks = 0; ks < 6; ks++) {
            A0[ks] = *(const short8*)(b0 + ks * 32);
            A1[ks] = *(const short8*)(b1 + ks * 32);
        }
    }
    const int j0 = 16 * w + 4 * quad;
    float s0[4] = {0,0,0,0}, q0[4] = {0,0,0,0}, s1[4] = {0,0,0,0}, q1[4] = {0,0,0,0};
    float scf[4], shf[4], scc[4], shc[4];
    if (MODE == 1) {
#pragma unroll
        for (int r = 0; r < 4; r++) {
            scf[r] = sc[j0 + r];        shf[r] = sc[128 + j0 + r];
            scc[r] = sc[64 + j0 + r];   shc[r] = sc[192 + j0 + r];
        }
    }
    for (int t = 0; t < 4; t++) {
        const u16* row = sTl + (16 * t + n16) * 200 + quad * 8;
        f32x4 acc0 = {0.f, 0.f, 0.f, 0.f}, acc1 = {0.f, 0.f, 0.f, 0.f};
#pragma unroll
        for (int ks = 0; ks < 6; ks++) {
            short8 b = *(const short8*)(row + ks * 32);
            acc0 = __builtin_amdgcn_mfma_f32_16x16x32_bf16(A0[ks], b, acc0, 0, 0, 0);
            acc1 = __builtin_amdgcn_mfma_f32_16x16x32_bf16(A1[ks], b, acc1, 0, 0, 0);
        }
        if (MODE == 0) {
#pragma unroll
            for (int r = 0; r < 4; r++) {
                s0[r] += acc0[r]; q0[r] = fmaf(acc0[r], acc0[r], q0[r]);
                s1[r] += acc1[r]; q1[r] = fmaf(acc1[r], acc1[r], q1[r]);
            }
        } else {
            int src = sSrc[16 * t + n16];
            float* dst = outbuf + (long)src * 64 + j0;
#pragma unroll
            for (int r = 0; r < 4; r++) {
                float f  = fmaf(acc0[r], scf[r], shf[r]);
                float cc = fmaf(acc1[r], scc[r], shc[r]);
                atomicAdd(dst + r, gate(f, cc));
            }
        }
    }
    if (MODE == 0) {
#pragma unroll
        for (int m = 1; m < 16; m <<= 1) {
#pragma unroll
            for (int r = 0; r < 4; r++) {
                s0[r] += __shfl_xor(s0[r], m); q0[r] += __shfl_xor(q0[r], m);
                s1[r] += __shfl_xor(s1[r], m); q1[r] += __shfl_xor(q1[r], m);
            }
        }
        if (n16 == 0) {
            float* sp = outbuf + (blockIdx.x & (NSPREAD - 1)) * 256;
#pragma unroll
            for (int r = 0; r < 4; r++) {
                atomicAdd(sp + j0 + r,       s0[r]);
                atomicAdd(sp + 128 + j0 + r, q0[r]);
                atomicAdd(sp + 64 + j0 + r,  s1[r]);
                atomicAdd(sp + 192 + j0 + r, q1[r]);
            }
        }
    }
}

// ---------------- bn1 finalize (fallback paths) ----------------
__global__ void k_bn1fin(const float* __restrict__ spread,
                         const float* __restrict__ g, const float* __restrict__ b,
                         float* __restrict__ sc)
{
    int c = threadIdx.x;  // 128
    float s = 0.f, q = 0.f;
    for (int k = 0; k < NSPREAD; k++) { s += spread[k * 256 + c]; q += spread[k * 256 + 128 + c]; }
    float mean_acc = s / (float)NE;
    float var = q / (float)NE - mean_acc * mean_acc;
    float scale = g[c] * rsqrtf(var + 1e-5f);
    sc[c] = scale;
    sc[128 + c] = b[c] - mean_acc * scale;
}

// ---------------- t4 gather: per-block bn1 coefs + gate + node sum -------------
__global__ __launch_bounds__(256) void k_scatter3(
    const u16* __restrict__ h, const int* __restrict__ ptr,
    const int* __restrict__ cnt, const float* __restrict__ spread,
    const float* __restrict__ g, const float* __restrict__ b,
    float* __restrict__ summed)
{
    __shared__ float ssc[256];
    int tid = threadIdx.x;
    if (tid < 128) {                       // recompute bn1 coefs (identical to k_bn1fin)
        int c = tid;
        float s = 0.f, q = 0.f;
        for (int k = 0; k < NSPREAD; k++) {
            s += spread[k * 256 + c]; q += spread[k * 256 + 128 + c];
        }
        float mean_acc = s / (float)NE;
        float var = q / (float)NE - mean_acc * mean_acc;
        float scale = g[c] * rsqrtf(var + 1e-5f);
        ssc[c] = scale;
        ssc[128 + c] = b[c] - mean_acc * scale;
    }
    __syncthreads();

    int n = blockIdx.x * 4 + (tid >> 6);
    int l = tid & 63;
    int es = l & 7, cg = l >> 3;

    float scf[8], shf[8], scc[8], shc[8];
#pragma unroll
    for (int j = 0; j < 8; j++) {
        scf[j] = ssc[cg * 8 + j];
        shf[j] = ssc[128 + cg * 8 + j];
        scc[j] = ssc[64 + cg * 8 + j];
        shc[j] = ssc[192 + cg * 8 + j];
    }

    int p0 = ptr[n], deg = cnt[n];
    float acc[8] = {0,0,0,0,0,0,0,0};
    for (int i = 0; i < deg; i += 8) {
        int idx = i + es;
        bool valid = idx < deg;
        int row = p0 + (valid ? idx : 0);
        const u16* hr = h + (long)row * 128;
        short8 f8 = *(const short8*)(hr + cg * 8);
        short8 c8 = *(const short8*)(hr + 64 + cg * 8);
#pragma unroll
        for (int j = 0; j < 8; j++) {
            float f  = fmaf(b2f((u16)f8[j]), scf[j], shf[j]);
            float cc = fmaf(b2f((u16)c8[j]), scc[j], shc[j]);
            float gg = gate(f, cc);
            acc[j] += valid ? gg : 0.f;
        }
    }
#pragma unroll
    for (int m = 1; m < 8; m <<= 1)
#pragma unroll
        for (int j = 0; j < 8; j++) acc[j] += __shfl_xor(acc[j], m);
    if (es == 0) {
        float* sp = summed + (long)n * 64 + cg * 8;
        float4 v0 = {acc[0], acc[1], acc[2], acc[3]};
        float4 v1 = {acc[4], acc[5], acc[6], acc[7]};
        *(float4*)sp = v0;
        *(float4*)(sp + 4) = v1;
    }
}

// ---------------- t3/t2 gather (fallback) --------------------------------------
__global__ __launch_bounds__(256) void k_scatter(
    const u16* __restrict__ h, const int* __restrict__ ptr,
    const int* __restrict__ cnt, const int* __restrict__ eidx,
    const float* __restrict__ sc, float* __restrict__ summed)
{
    int tid = threadIdx.x;
    int n = blockIdx.x * 4 + (tid >> 6);
    int l = tid & 63;
    int es = l & 7, cg = l >> 3;

    float4 a0 = *(const float4*)(sc + cg * 8);
    float4 a1 = *(const float4*)(sc + cg * 8 + 4);
    float4 b0 = *(const float4*)(sc + 128 + cg * 8);
    float4 b1 = *(const float4*)(sc + 128 + cg * 8 + 4);
    float4 c0 = *(const float4*)(sc + 64 + cg * 8);
    float4 c1 = *(const float4*)(sc + 64 + cg * 8 + 4);
    float4 d0 = *(const float4*)(sc + 192 + cg * 8);
    float4 d1 = *(const float4*)(sc + 192 + cg * 8 + 4);
    float scf[8] = {a0.x,a0.y,a0.z,a0.w,a1.x,a1.y,a1.z,a1.w};
    float shf[8] = {b0.x,b0.y,b0.z,b0.w,b1.x,b1.y,b1.z,b1.w};
    float scc[8] = {c0.x,c0.y,c0.z,c0.w,c1.x,c1.y,c1.z,c1.w};
    float shc[8] = {d0.x,d0.y,d0.z,d0.w,d1.x,d1.y,d1.z,d1.w};

    int p0 = ptr[n], deg = cnt[n];
    float acc[8] = {0,0,0,0,0,0,0,0};
    for (int i = 0; i < deg; i += 8) {
        int idx = i + es;
        bool valid = idx < deg;
        int e = eidx[p0 + (valid ? idx : 0)];
        const u16* hr = h + (long)e * 128;
        short8 f8 = *(const short8*)(hr + cg * 8);
        short8 c8 = *(const short8*)(hr + 64 + cg * 8);
#pragma unroll
        for (int j = 0; j < 8; j++) {
            float f  = fmaf(b2f((u16)f8[j]), scf[j], shf[j]);
            float cc = fmaf(b2f((u16)c8[j]), scc[j], shc[j]);
            float gg = gate(f, cc);
            acc[j] += valid ? gg : 0.f;
        }
    }
#pragma unroll
    for (int m = 1; m < 8; m <<= 1)
#pragma unroll
        for (int j = 0; j < 8; j++) acc[j] += __shfl_xor(acc[j], m);
    if (es == 0) {
        float* sp = summed + (long)n * 64 + cg * 8;
        float4 v0 = {acc[0], acc[1], acc[2], acc[3]};
        float4 v1 = {acc[4], acc[5], acc[6], acc[7]};
        *(float4*)sp = v0;
        *(float4*)(sp + 4) = v1;
    }
}

// ---------------- bn2 stats ----------------
__global__ __launch_bounds__(256) void k_bn2stats(const float* __restrict__ summed,
                                                  float* __restrict__ acc2)
{
    int tid = threadIdx.x; int c = tid & 63; int sub = tid >> 6;
    float s = 0.f, q = 0.f;
    for (int r = blockIdx.x * 4 + sub; r < NN; r += 4 * 128) {
        float v = summed[(long)r * 64 + c]; s += v; q = fmaf(v, v, q);
    }
    __shared__ float rs[256], rq[256];
    rs[tid] = s; rq[tid] = q; __syncthreads();
    if (tid < 64) {
        s = rs[tid] + rs[tid + 64] + rs[tid + 128] + rs[tid + 192];
        q = rq[tid] + rq[tid + 64] + rq[tid + 128] + rq[tid + 192];
        atomicAdd(&acc2[tid], s);
        atomicAdd(&acc2[64 + tid], q);
    }
}

// bn2 coefs + out_b init (fallback paths)
__global__ void k_bn2fin(const float* __restrict__ acc2,
                         const float* __restrict__ g, const float* __restrict__ b,
                         float* __restrict__ sc2, const float* __restrict__ outb,
                         float* __restrict__ out)
{
    int c = threadIdx.x;  // 256
    if (c < 64) {
        float mean = acc2[c] / (float)NN;
        float var = acc2[64 + c] / (float)NN - mean * mean;
        float scale = g[c] * rsqrtf(var + 1e-5f);
        sc2[c] = scale;
        sc2[64 + c] = b[c] - mean * scale;
    }
    out[(long)NN * 64 + c] = outb[0];
}

// ---------------- t4: atom_out + silu + logits + segmax, bn2 coefs per block ---
__global__ __launch_bounds__(256) void k_nodepost2(
    const float* __restrict__ summed, const float* __restrict__ acc2,
    const float* __restrict__ g, const float* __restrict__ b,
    const float* __restrict__ attW, const float* __restrict__ attb,
    const int* __restrict__ batch, float* __restrict__ out,
    float* __restrict__ elog, unsigned* __restrict__ segmax)
{
    __shared__ float ssc2[128];
    int tid = threadIdx.x;
    if (tid < 64) {                        // identical to k_bn2fin
        float mean = acc2[tid] / (float)NN;
        float var = acc2[64 + tid] / (float)NN - mean * mean;
        float scale = g[tid] * rsqrtf(var + 1e-5f);
        ssc2[tid] = scale;
        ssc2[64 + tid] = b[tid] - mean * scale;
    }
    __syncthreads();

    int n = blockIdx.x * 4 + (tid >> 6); int c = tid & 63;
    float v = summed[(long)n * 64 + c];
    float ao = fmaf(v, ssc2[c], ssc2[64 + c]);
    out[(long)n * 64 + c] = ao;
    float h = fsilu(ao);
    float p = h * attW[c];
#pragma unroll
    for (int off = 32; off; off >>= 1) p += __shfl_down(p, off, 64);
    if (c == 0) {
        float logit = p + attb[0];
        elog[n] = logit;
        unsigned u = __float_as_uint(logit);
        u = (u & 0x80000000u) ? ~u : (u | 0x80000000u);
        atomicMax(&segmax[batch[n]], u);
    }
}

// fallback nodepost
__global__ __launch_bounds__(256) void k_nodepost(
    const float* __restrict__ summed, const float* __restrict__ sc2,
    const float* __restrict__ attW, const float* __restrict__ attb,
    const int* __restrict__ batch, float* __restrict__ out,
    float* __restrict__ elog, unsigned* __restrict__ segmax)
{
    int tid = threadIdx.x; int n = blockIdx.x * 4 + (tid >> 6); int c = tid & 63;
    float v = summed[(long)n * 64 + c];
    float ao = fmaf(v, sc2[c], sc2[64 + c]);
    out[(long)n * 64 + c] = ao;
    float h = fsilu(ao);
    float p = h * attW[c];
#pragma unroll
    for (int off = 32; off; off >>= 1) p += __shfl_down(p, off, 64);
    if (c == 0) {
        float logit = p + attb[0];
        elog[n] = logit;
        unsigned u = __float_as_uint(logit);
        u = (u & 0x80000000u) ? ~u : (u | 0x80000000u);
        atomicMax(&segmax[batch[n]], u);
    }
}

// t4: denom + crys out_b init
__global__ void k_denom2(const int* __restrict__ batch,
                         const unsigned* __restrict__ segmax,
                         float* __restrict__ elog, float* __restrict__ denom,
                         const float* __restrict__ outb, float* __restrict__ out)
{
    int n = blockIdx.x * 256 + threadIdx.x;
    if (n < NG) out[(long)NN * 64 + n] = outb[0];
    if (n >= NN) return;
    int b = batch[n];
    unsigned u = segmax[b];
    u = (u & 0x80000000u) ? (u & 0x7FFFFFFFu) : ~u;
    float e = __expf(elog[n] - __uint_as_float(u));
    elog[n] = e;
    atomicAdd(&denom[b], e);
}

__global__ void k_denom(const int* __restrict__ batch,
                        const unsigned* __restrict__ segmax,
                        float* __restrict__ elog, float* __restrict__ denom)
{
    int n = blockIdx.x * 256 + threadIdx.x;
    if (n >= NN) return;
    int b = batch[n];
    unsigned u = segmax[b];
    u = (u & 0x80000000u) ? (u & 0x7FFFFFFFu) : ~u;
    float e = __expf(elog[n] - __uint_as_float(u));
    elog[n] = e;
    atomicAdd(&denom[b], e);
}

// weighted pooling fused with out_W projection
__global__ __launch_bounds__(256) void k_crys(
    const float* __restrict__ atom_out, const float* __restrict__ elog,
    const float* __restrict__ denom, const int* __restrict__ batch,
    const float* __restrict__ outW, float* __restrict__ out)
{
    int tid = threadIdx.x; int n = blockIdx.x * 4 + (tid >> 6); int l = tid & 63;
    int b = batch[n];
    float alpha = elog[n] / denom[b];
    float ao = atom_out[(long)n * 64 + l];
    float p = fsilu(ao) * outW[l];
#pragma unroll
    for (int off = 32; off; off >>= 1) p += __shfl_down(p, off, 64);
    if (l == 0) atomicAdd(&out[(long)NN * 64 + b], alpha * p);
}

extern "C" void kernel_launch(void* const* d_in, const int* in_sizes, int n_in,
                              void* d_out, int out_size, void* d_ws, size_t ws_size,
                              hipStream_t stream)
{
    const float* x    = (const float*)d_in[0];
    const float* eatt = (const float*)d_in[1];
    const float* lf   = (const float*)d_in[2];
    const int*   ei   = (const int*)d_in[3];
    const int*   batch= (const int*)d_in[4];
    const float* embW = (const float*)d_in[5];
    const float* embB = (const float*)d_in[6];
    const float* fcW  = (const float*)d_in[7];
    // d_in[8] fc_b folds into bn1 shift
    const float* bn1g = (const float*)d_in[9];
    const float* bn1b = (const float*)d_in[10];
    const float* bn2g = (const float*)d_in[11];
    const float* bn2b = (const float*)d_in[12];
    const float* attW = (const float*)d_in[13];
    const float* attB = (const float*)d_in[14];
    const float* outW = (const float*)d_in[15];
    const float* outB = (const float*)d_in[16];
    float* out = (float*)d_out;
    float* ws  = (float*)d_ws;

    u16* afb  = (u16*)(ws + OFF_AFB);
    u16* wT   = (u16*)(ws + OFF_WT);
    int* cnt  = (int*)(ws + OFF_CNT);
    int* ptr  = (int*)(ws + OFF_PTR);
    int* head = (int*)(ws + OFF_HEAD);
    int* bsum = (int*)(ws + OFF_BSUM);
    int* bofs = (int*)(ws + OFF_BOFS);
    int* eidx = (int*)(ws + OFF_EIDX);
    u16* h    = (u16*)(ws + OFF_H);

    const bool t4 = ws_size >= (size_t)OFF_T4_END * sizeof(float);
    const bool t3 = ws_size >= (size_t)OFF_T3_END * sizeof(float);
    const bool t2 = ws_size >= (size_t)OFF_T2_END * sizeof(float);

    if (t4) {
        u16* wT3  = wT;
        u16* wP   = wT + 8192;
        float* P  = ws + OFF_P;
        int* srcC = (int*)(ws + OFF_SRCC);
        int* dstC = (int*)(ws + OFF_DSTC);
        u16* eaB  = (u16*)(ws + OFF_EAB);
        k_embed2<<<12500, 256, 0, stream>>>(x, lf, embW, embB, afb, fcW, wT3, wP, ws);
        k_hist<<<(NE + 255) / 256, 256, 0, stream>>>(ei, cnt);
        k_scan1b<<<1, 1024, 0, stream>>>(cnt, ptr, head);
        k_fill3<<<(NE + 255) / 256, 256, 0, stream>>>(ei, eatt, head, srcC, dstC, eaB);
        k_pnode<1><<<(NN + 63) / 64, 256, 0, stream>>>(afb, wP, P);
        k_gemm_h4<<<NE / 64, 256, 0, stream>>>(eaB, srcC, dstC, wT3, P, h,
                                               ws + OFF_BN1SPR);
        k_scatter3<<<NN / 4, 256, 0, stream>>>(h, ptr, cnt, ws + OFF_BN1SPR,
                                               bn1g, bn1b, ws + OFF_SUMMED);
        k_bn2stats<<<128, 256, 0, stream>>>(ws + OFF_SUMMED, ws + OFF_BN2ACC);
        k_nodepost2<<<12500, 256, 0, stream>>>(ws + OFF_SUMMED, ws + OFF_BN2ACC,
                                               bn2g, bn2b, attW, attB, batch, out,
                                               ws + OFF_ELOG,
                                               (unsigned*)(ws + OFF_SEGMAX));
        k_denom2<<<196, 256, 0, stream>>>(batch, (const unsigned*)(ws + OFF_SEGMAX),
                                          ws + OFF_ELOG, ws + OFF_DENOM, outB, out);
        k_crys<<<12500, 256, 0, stream>>>(out, ws + OFF_ELOG, ws + OFF_DENOM, batch,
                                          outW, out);
        return;
    }

    k_embed<<<12500, 256, 0, stream>>>(x, lf, embW, embB, afb);

    if (t3) {
        u16* wT3 = wT;
        u16* wP  = wT + 8192;
        float* P = ws + OFF_P;
        k_prepw2<<<96, 256, 0, stream>>>(fcW, wT3, wP);
        hipMemsetAsync(ws + OFF_BN1SPR, 0,
                       (size_t)(OFF_PTR - OFF_BN1SPR) * sizeof(float), stream);
        k_hist<<<(NE + 255) / 256, 256, 0, stream>>>(ei, cnt);
        k_partial<<<(NN + SCAN_B - 1) / SCAN_B, SCAN_B, 0, stream>>>(cnt, ptr, bsum);
        k_scanb<<<1, 256, 0, stream>>>(bsum, bofs, (NN + SCAN_B - 1) / SCAN_B);
        k_addofs<<<(NN + 255) / 256, 256, 0, stream>>>(ptr, bofs, head);
        k_fill<<<(NE + 255) / 256, 256, 0, stream>>>(ei, head, eidx);
        k_pnode<0><<<(NN + 63) / 64, 256, 0, stream>>>(afb, wP, P);
        k_gemm_h2<<<NE / 64, 256, 0, stream>>>(eatt, ei, wT3, P, h, ws + OFF_BN1SPR);
        k_bn1fin<<<1, 128, 0, stream>>>(ws + OFF_BN1SPR, bn1g, bn1b, ws + OFF_BN1SC);
        k_scatter<<<NN / 4, 256, 0, stream>>>(h, ptr, cnt, eidx, ws + OFF_BN1SC,
                                              ws + OFF_SUMMED);
    } else if (t2) {
        k_prepw<<<96, 256, 0, stream>>>(fcW, wT);
        hipMemsetAsync(ws + OFF_BN1SPR, 0,
                       (size_t)(OFF_PTR - OFF_BN1SPR) * sizeof(float), stream);
        k_hist<<<(NE + 255) / 256, 256, 0, stream>>>(ei, cnt);
        k_partial<<<(NN + SCAN_B - 1) / SCAN_B, SCAN_B, 0, stream>>>(cnt, ptr, bsum);
        k_scanb<<<1, 256, 0, stream>>>(bsum, bofs, (NN + SCAN_B - 1) / SCAN_B);
        k_addofs<<<(NN + 255) / 256, 256, 0, stream>>>(ptr, bofs, head);
        k_fill<<<(NE + 255) / 256, 256, 0, stream>>>(ei, head, eidx);
        k_gemm_h<<<NE / 64, 256, 0, stream>>>(afb, eatt, ei, wT, h, ws + OFF_BN1SPR);
        k_bn1fin<<<1, 128, 0, stream>>>(ws + OFF_BN1SPR, bn1g, bn1b, ws + OFF_BN1SC);
        k_scatter<<<NN / 4, 256, 0, stream>>>(h, ptr, cnt, eidx, ws + OFF_BN1SC,
                                              ws + OFF_SUMMED);
    } else {
        k_prepw<<<96, 256, 0, stream>>>(fcW, wT);
        hipMemsetAsync(ws + OFF_SUMMED, 0,
                       (size_t)(OFF_PTR - OFF_SUMMED) * sizeof(float), stream);
        k_gemm<0><<<NE / 64, 256, 0, stream>>>(afb, eatt, ei, wT, ws + OFF_BN1SC,
                                               ws + OFF_BN1SPR);
        k_bn1fin<<<1, 128, 0, stream>>>(ws + OFF_BN1SPR, bn1g, bn1b, ws + OFF_BN1SC);
        k_gemm<1><<<NE / 64, 256, 0, stream>>>(afb, eatt, ei, wT, ws + OFF_BN1SC,
                                               ws + OFF_SUMMED);
    }

    k_bn2stats<<<128, 256, 0, stream>>>(ws + OFF_SUMMED, ws + OFF_BN2ACC);
    k_bn2fin<<<1, 256, 0, stream>>>(ws + OFF_BN2ACC, bn2g, bn2b, ws + OFF_BN2SC,
                                    outB, out);
    k_nodepost<<<12500, 256, 0, stream>>>(ws + OFF_SUMMED, ws + OFF_BN2SC, attW, attB,
                                          batch, out, ws + OFF_ELOG,
                                          (unsigned*)(ws + OFF_SEGMAX));
    k_denom<<<196, 256, 0, stream>>>(batch, (const unsigned*)(ws + OFF_SEGMAX),
                                     ws + OFF_ELOG, ws + OFF_DENOM);
    k_crys<<<12500, 256, 0, stream>>>(out, ws + OFF_ELOG, ws + OFF_DENOM, batch,
                                      outW, out);
}

// Round 4
// 1194.033 us; speedup vs baseline: 1.0716x; 1.0716x over previous
//
#include <hip/hip_runtime.h>
#include <math.h>

#define NN 50000
#define NE 1000000
#define NG 256
#define ORIGD 92
#define NBRD 41
#define NSPREAD 32
#define SCAN_B 256

typedef unsigned short u16;
typedef __attribute__((ext_vector_type(8))) short short8;   // 8 x bf16 MFMA frag
typedef __attribute__((ext_vector_type(4))) float f32x4;    // MFMA accumulator
typedef __attribute__((ext_vector_type(8))) float f32x8;    // packed P chunk

// ---- workspace layout (float offsets) ----
#define OFF_AFB     0                        // 50000*64 bf16
#define OFF_SUMMED  1600000                  // 50000*64 fp32
#define OFF_WT      4800000                  // t2: 128x192 bf16 | t3/t4: wT3 128x64 + wP 256x64
#define OFF_BN1SPR  4812288                  // 32*256
#define OFF_BN1SC   4820480                  // 256 (fallback paths only)
#define OFF_BN2ACC  4820736                  // 128
#define OFF_BN2SC   4820864                  // 128 (fallback paths only)
#define OFF_ELOG    4820992                  // 50000
#define OFF_SEGMAX  4870992                  // 256
#define OFF_DENOM   4871248                  // 256
#define OFF_CNT     4871504                  // 50000 int
#define OFF_PTR     4921504                  // 50000 int
#define OFF_HEAD    4971504                  // 50000 int
#define OFF_BSUM    5021504                  // 256 int
#define OFF_BOFS    5021760                  // 256 int
#define OFF_EIDX    5022016                  // 1M int (edge id per CSR position)
#define OFF_H       6022016                  // 1M*128 bf16 (256 MB)
#define OFF_T2_END  70022016
#define OFF_P       70022016                 // t3/t4: 50000*256 fp32 node pre-proj
#define OFF_T3_END  82822016
#define OFF_SRCC    82822016                 // t4: 1M int src in CSR order
#define OFF_DSTC    83822016                 // t4: 1M int dst in CSR order
#define OFF_EAB     84822016                 // t4: 1M*48 bf16 edge_attr (EDGE order)
#define OFF_T4_END  108822016

__device__ __forceinline__ u16 f2b(float f) {          // fp32 -> bf16 RNE
    unsigned u = __float_as_uint(f);
    return (u16)((u + 0x7FFFu + ((u >> 16) & 1u)) >> 16);
}
__device__ __forceinline__ float b2f(u16 u) {
    return __uint_as_float(((unsigned)u) << 16);
}
__device__ __forceinline__ float gate(float f, float cc) {
    float sig = __builtin_amdgcn_rcpf(1.f + __expf(-f));
    float sp  = fmaxf(cc, 0.f) + __logf(1.f + __expf(-fabsf(cc)));
    return sig * sp;
}
__device__ __forceinline__ float fsilu(float x) {
    return x * __builtin_amdgcn_rcpf(1.f + __expf(-x));
}

// ---------------- t4 mega-prolog: embed + weight prep + workspace zeroing ------
// zero region A = [BN1SPR, ELOG) 8704 words; region B = [SEGMAX, PTR) 50512 words
__global__ __launch_bounds__(256) void k_embed2(
    const float* __restrict__ x, const float* __restrict__ lf,
    const float* __restrict__ W, const float* __restrict__ b,
    u16* __restrict__ afb, const float* __restrict__ fcW,
    u16* __restrict__ wT3, u16* __restrict__ wP, float* __restrict__ ws)
{
    int gid = blockIdx.x * 256 + threadIdx.x;
    int n = gid >> 6, c = gid & 63;
    const float* xr = x + (long)n * ORIGD;
    float acc = b[c] + lf[gid];
#pragma unroll 4
    for (int k = 0; k < ORIGD; k++)
        acc = fmaf(xr[k], W[k * 64 + c], acc);
    afb[gid] = f2b(acc);

    if (blockIdx.x < 96) {                      // prepw2 work
        int i = blockIdx.x * 256 + threadIdx.x; // 24576 = 8192 + 16384
        if (i < 8192) {
            int j = i >> 6, k = i & 63;
            wT3[i] = (k < NBRD) ? f2b(fcW[(128 + k) * 128 + j]) : (u16)0;
        } else {
            int i2 = i - 8192;
            int j = i2 >> 6, k = i2 & 63;
            int row = (j < 128) ? k : (64 + k);
            wP[i2] = f2b(fcW[row * 128 + (j & 127)]);
        }
    } else if (blockIdx.x < 336) {              // zeroing work
        int zid = (blockIdx.x - 96) * 256 + threadIdx.x;
        if (zid < 8704) {
            ws[OFF_BN1SPR + zid] = 0.f;
        } else {
            int z2 = zid - 8704;
            if (z2 < 50512) ws[OFF_SEGMAX + z2] = 0.f;
        }
    }
}

// ---------------- prep (t2 path) ----
__global__ void k_prepw(const float* __restrict__ fcW, u16* __restrict__ wT)
{
    int i = blockIdx.x * 256 + threadIdx.x;        // 24576
    int j = i / 192, k = i - j * 192;
    wT[i] = (k < 169) ? f2b(fcW[k * 128 + j]) : (u16)0;
}

// ---------------- prep (t3 fallback) ----
__global__ void k_prepw2(const float* __restrict__ fcW, u16* __restrict__ wT3,
                         u16* __restrict__ wP)
{
    int i = blockIdx.x * 256 + threadIdx.x;
    if (i < 8192) {
        int j = i >> 6, k = i & 63;
        wT3[i] = (k < NBRD) ? f2b(fcW[(128 + k) * 128 + j]) : (u16)0;
    } else {
        int i2 = i - 8192;
        int j = i2 >> 6, k = i2 & 63;
        int row = (j < 128) ? k : (64 + k);
        wP[i2] = f2b(fcW[row * 128 + (j & 127)]);
    }
}

// ---------------- t2/t3 fallback embed ----
__global__ __launch_bounds__(256) void k_embed(
    const float* __restrict__ x, const float* __restrict__ lf,
    const float* __restrict__ W, const float* __restrict__ b,
    u16* __restrict__ afb)
{
    int gid = blockIdx.x * 256 + threadIdx.x;
    int n = gid >> 6, c = gid & 63;
    const float* xr = x + (long)n * ORIGD;
    float acc = b[c] + lf[gid];
#pragma unroll 4
    for (int k = 0; k < ORIGD; k++)
        acc = fmaf(xr[k], W[k * 64 + c], acc);
    afb[gid] = f2b(acc);
}

// ---------------- node pre-projection --------------------------------------
// PACKED=1 (t4): P[n][jp] groups each (w,quad) lane's 8 channels into one 32B chunk.
// PACKED=0 (t3): plain column order.
template <int PACKED>
__global__ __launch_bounds__(256) void k_pnode(
    const u16* __restrict__ afb, const u16* __restrict__ wP, float* __restrict__ P)
{
    __shared__ __align__(16) u16 sB[64 * 72];
    const int tid = threadIdx.x;
    const int n0 = blockIdx.x * 64;

    for (int i = tid; i < 512; i += 256) {
        int r = i >> 3, c = i & 7;
        int n = n0 + r;
        short8 v = {0,0,0,0,0,0,0,0};
        if (n < NN) v = *(const short8*)(afb + (long)n * 64 + c * 8);
        *(short8*)(sB + r * 72 + c * 8) = v;
    }
    __syncthreads();

    const int lane = tid & 63, w = tid >> 6;
    const int n16 = lane & 15, quad = lane >> 4;
    short8 A[4][2];
#pragma unroll
    for (int m = 0; m < 4; m++) {
        const u16* base = wP + (16 * (w + 4 * m) + n16) * 64 + quad * 8;
        A[m][0] = *(const short8*)(base);
        A[m][1] = *(const short8*)(base + 32);
    }
    for (int t = 0; t < 4; t++) {
        const u16* row = sB + (16 * t + n16) * 72 + quad * 8;
        short8 b0 = *(const short8*)(row);
        short8 b1 = *(const short8*)(row + 32);
        int n = n0 + 16 * t + n16;
#pragma unroll
        for (int m = 0; m < 4; m++) {
            f32x4 acc = {0.f, 0.f, 0.f, 0.f};
            acc = __builtin_amdgcn_mfma_f32_16x16x32_bf16(A[m][0], b0, acc, 0, 0, 0);
            acc = __builtin_amdgcn_mfma_f32_16x16x32_bf16(A[m][1], b1, acc, 0, 0, 0);
            if (n < NN) {
                int M = w + 4 * m;
                int j;
                if (PACKED) {
                    int MM = M & 7;
                    j = ((M >> 3) * 128) + ((MM & 3) * 4 + quad) * 8 + ((MM >> 2) << 2);
                } else {
                    j = 16 * M + 4 * quad;
                }
                *(f32x4*)(P + (long)n * 256 + j) = acc;
            }
        }
    }
}

// ---------------- CSR build ----------------
__global__ void k_hist(const int* __restrict__ ei, int* __restrict__ cnt)
{
    int e = blockIdx.x * 256 + threadIdx.x;
    if (e < NE) atomicAdd(&cnt[ei[e]], 1);
}

// t4: hist fused with ea->bf16 conversion in EDGE order (coalesced both sides).
// 6 threads per edge; thread q==0 also does the degree histogram atomic.
__global__ __launch_bounds__(256) void k_hist2(
    const int* __restrict__ ei, const float* __restrict__ ea,
    int* __restrict__ cnt, u16* __restrict__ eaB)
{
    long gid = (long)blockIdx.x * 256 + threadIdx.x;
    if (gid >= (long)NE * 6) return;
    int e = (int)(gid / 6);
    int q = (int)(gid - (long)e * 6);
    if (q == 0) atomicAdd(&cnt[ei[e]], 1);
    const float* row = ea + (long)e * NBRD;
    int c0 = q * 8;
    short8 v;
#pragma unroll
    for (int j = 0; j < 8; j++) {
        int c = c0 + j;
        v[j] = (c < NBRD) ? (short)f2b(row[c]) : (short)0;
    }
    *(short8*)(eaB + (long)e * 48 + c0) = v;
}

// parallel scan (restored)
__global__ void k_partial(const int* __restrict__ cnt, int* __restrict__ lofs,
                          int* __restrict__ bsum)
{
    __shared__ int sd[SCAN_B];
    int t = threadIdx.x, b = blockIdx.x, n = b * SCAN_B + t;
    int v = (n < NN) ? cnt[n] : 0;
    sd[t] = v; __syncthreads();
    for (int o = 1; o < SCAN_B; o <<= 1) {
        int x = (t >= o) ? sd[t - o] : 0;
        __syncthreads();
        sd[t] += x;
        __syncthreads();
    }
    if (n < NN) lofs[n] = sd[t] - v;
    if (t == SCAN_B - 1) bsum[b] = sd[t];
}

__global__ void k_scanb(const int* __restrict__ bsum, int* __restrict__ bofs, int nb)
{
    __shared__ int sd[256];
    int t = threadIdx.x;
    int v = (t < nb) ? bsum[t] : 0;
    sd[t] = v; __syncthreads();
    for (int o = 1; o < 256; o <<= 1) {
        int x = (t >= o) ? sd[t - o] : 0;
        __syncthreads();
        sd[t] += x;
        __syncthreads();
    }
    bofs[t] = sd[t] - v;
}

__global__ void k_addofs(int* __restrict__ ptr, const int* __restrict__ bofs,
                         int* __restrict__ head)
{
    int n = blockIdx.x * 256 + threadIdx.x;
    if (n < NN) {
        int p = ptr[n] + bofs[n >> 8];
        ptr[n] = p; head[n] = p;
    }
}

__global__ void k_fill(const int* __restrict__ ei, int* __restrict__ head,
                       int* __restrict__ eidx)
{
    int e = blockIdx.x * 256 + threadIdx.x;
    if (e < NE) {
        int pos = atomicAdd(&head[ei[e]], 1);
        eidx[pos] = e;
    }
}

// t4: CSR fill, 4-B scattered writes only (eidx + src/dst in CSR order)
__global__ void k_fill2(const int* __restrict__ ei, int* __restrict__ head,
                        int* __restrict__ eidx, int* __restrict__ srcC,
                        int* __restrict__ dstC)
{
    int e = blockIdx.x * 256 + threadIdx.x;
    if (e < NE) {
        int s = ei[e];
        int pos = atomicAdd(&head[s], 1);
        eidx[pos] = e;
        srcC[pos] = s;
        dstC[pos] = ei[NE + e];
    }
}

// ---------------- t4 edge pass: CSR order, packed P, depth-2 pipelined ---------
__global__ __launch_bounds__(256, 4) void k_gemm_h5(
    const u16* __restrict__ eaB, const int* __restrict__ eidx,
    const int* __restrict__ srcC, const int* __restrict__ dstC,
    const u16* __restrict__ wT3, const float* __restrict__ P,
    u16* __restrict__ h, float* __restrict__ spread)
{
    const int tid = threadIdx.x;
    const int e0 = blockIdx.x * 64;
    const int lane = tid & 63, w = tid >> 6;
    const int n16 = lane & 15, quad = lane >> 4;

    short8 A0[2], A1[2];
    {
        const u16* a0 = wT3 + (16 * w + n16) * 64 + quad * 8;
        const u16* a1 = wT3 + (16 * (w + 4) + n16) * 64 + quad * 8;
        A0[0] = *(const short8*)(a0);  A0[1] = *(const short8*)(a0 + 32);
        A1[0] = *(const short8*)(a1);  A1[1] = *(const short8*)(a1 + 32);
    }

    const int j0 = 16 * w + 4 * quad;
    const int pofs = (w * 4 + quad) * 8;
    const short8 bz = {0,0,0,0,0,0,0,0};
    float s0[4] = {0,0,0,0}, q0[4] = {0,0,0,0}, s1[4] = {0,0,0,0}, q1[4] = {0,0,0,0};

    short8 b0A, b1A, b0B, b1B;
    f32x8 gSA, gDA, gSB, gDB;

#define LOADT(t, b0v, b1v, gSv, gDv)                                       \
    {                                                                      \
        int p_ = e0 + 16 * (t) + n16;                                      \
        int s_ = srcC[p_], d_ = dstC[p_], e_ = eidx[p_];                   \
        const u16* er_ = eaB + (long)e_ * 48;                              \
        b0v = *(const short8*)(er_ + quad * 8);                            \
        b1v = (quad < 2) ? *(const short8*)(er_ + 32 + quad * 8) : bz;     \
        gSv = *(const f32x8*)(P + (long)s_ * 256 + pofs);                  \
        gDv = *(const f32x8*)(P + (long)d_ * 256 + 128 + pofs);            \
    }

#define COMPT(t, b0v, b1v, gSv, gDv)                                       \
    {                                                                      \
        f32x4 acc0 = {0.f,0.f,0.f,0.f}, acc1 = {0.f,0.f,0.f,0.f};          \
        acc0 = __builtin_amdgcn_mfma_f32_16x16x32_bf16(A0[0], b0v, acc0, 0, 0, 0); \
        acc0 = __builtin_amdgcn_mfma_f32_16x16x32_bf16(A0[1], b1v, acc0, 0, 0, 0); \
        acc1 = __builtin_amdgcn_mfma_f32_16x16x32_bf16(A1[0], b0v, acc1, 0, 0, 0); \
        acc1 = __builtin_amdgcn_mfma_f32_16x16x32_bf16(A1[1], b1v, acc1, 0, 0, 0); \
        u16 hv0[4], hv1[4];                                                \
        _Pragma("unroll")                                                  \
        for (int r = 0; r < 4; r++) {                                      \
            float u0 = acc0[r] + gSv[r] + gDv[r];                          \
            float u1 = acc1[r] + gSv[4 + r] + gDv[4 + r];                  \
            s0[r] += u0; q0[r] = fmaf(u0, u0, q0[r]);                      \
            s1[r] += u1; q1[r] = fmaf(u1, u1, q1[r]);                      \
            hv0[r] = f2b(u0); hv1[r] = f2b(u1);                            \
        }                                                                  \
        u16* hp = h + (long)(e0 + 16 * (t) + n16) * 128 + j0;              \
        ushort4 v0 = make_ushort4(hv0[0], hv0[1], hv0[2], hv0[3]);         \
        ushort4 v1 = make_ushort4(hv1[0], hv1[1], hv1[2], hv1[3]);         \
        *(ushort4*)hp = v0;                                                \
        *(ushort4*)(hp + 64) = v1;                                         \
    }

    LOADT(0, b0A, b1A, gSA, gDA);
    LOADT(1, b0B, b1B, gSB, gDB);
    COMPT(0, b0A, b1A, gSA, gDA);
    LOADT(2, b0A, b1A, gSA, gDA);
    COMPT(1, b0B, b1B, gSB, gDB);
    LOADT(3, b0B, b1B, gSB, gDB);
    COMPT(2, b0A, b1A, gSA, gDA);
    COMPT(3, b0B, b1B, gSB, gDB);

#undef LOADT
#undef COMPT

#pragma unroll
    for (int m = 1; m < 16; m <<= 1) {
#pragma unroll
        for (int r = 0; r < 4; r++) {
            s0[r] += __shfl_xor(s0[r], m); q0[r] += __shfl_xor(q0[r], m);
            s1[r] += __shfl_xor(s1[r], m); q1[r] += __shfl_xor(q1[r], m);
        }
    }
    if (n16 == 0) {
        float* sp = spread + (blockIdx.x & (NSPREAD - 1)) * 256;
#pragma unroll
        for (int r = 0; r < 4; r++) {
            atomicAdd(sp + j0 + r,       s0[r]);
            atomicAdd(sp + 128 + j0 + r, q0[r]);
            atomicAdd(sp + 64 + j0 + r,  s1[r]);
            atomicAdd(sp + 192 + j0 + r, q1[r]);
        }
    }
}

// ---------------- t3 edge pass (fallback) -------------------------------------
__global__ __launch_bounds__(256) void k_gemm_h2(
    const float* __restrict__ ea, const int* __restrict__ ei,
    const u16* __restrict__ wT3, const float* __restrict__ P,
    u16* __restrict__ h, float* __restrict__ spread)
{
    __shared__ __align__(16) u16 sTl[64 * 72];
    __shared__ int sSrc[64], sDst[64];
    const int tid = threadIdx.x;
    const int e0 = blockIdx.x * 64;

    if (tid < 64) sSrc[tid] = ei[e0 + tid];
    else if (tid < 128) sDst[tid - 64] = ei[NE + e0 + tid - 64];

    for (int i = tid; i < 64 * 64; i += 256) {
        int e = i >> 6, c = i & 63;
        float v = (c < NBRD) ? ea[(long)(e0 + e) * NBRD + c] : 0.f;
        sTl[e * 72 + c] = f2b(v);
    }
    __syncthreads();

    const int lane = tid & 63, w = tid >> 6;
    const int n16 = lane & 15, quad = lane >> 4;

    short8 A0[2], A1[2];
    {
        const u16* b0 = wT3 + (16 * w + n16) * 64 + quad * 8;
        const u16* b1 = wT3 + (16 * (w + 4) + n16) * 64 + quad * 8;
        A0[0] = *(const short8*)(b0);  A0[1] = *(const short8*)(b0 + 32);
        A1[0] = *(const short8*)(b1);  A1[1] = *(const short8*)(b1 + 32);
    }

    const int j0 = 16 * w + 4 * quad;
    float s0[4] = {0,0,0,0}, q0[4] = {0,0,0,0}, s1[4] = {0,0,0,0}, q1[4] = {0,0,0,0};

    for (int t = 0; t < 4; t++) {
        const int ge16 = 16 * t + n16;
        const int src = sSrc[ge16], dst = sDst[ge16];
        const float* pS = P + (long)src * 256;
        const float* pD = P + (long)dst * 256 + 128;
        f32x4 g0 = *(const f32x4*)(pS + j0);
        f32x4 g1 = *(const f32x4*)(pS + 64 + j0);
        f32x4 g2 = *(const f32x4*)(pD + j0);
        f32x4 g3 = *(const f32x4*)(pD + 64 + j0);

        const u16* row = sTl + ge16 * 72 + quad * 8;
        short8 b0 = *(const short8*)(row);
        short8 b1 = *(const short8*)(row + 32);
        f32x4 acc0 = {0.f, 0.f, 0.f, 0.f}, acc1 = {0.f, 0.f, 0.f, 0.f};
        acc0 = __builtin_amdgcn_mfma_f32_16x16x32_bf16(A0[0], b0, acc0, 0, 0, 0);
        acc0 = __builtin_amdgcn_mfma_f32_16x16x32_bf16(A0[1], b1, acc0, 0, 0, 0);
        acc1 = __builtin_amdgcn_mfma_f32_16x16x32_bf16(A1[0], b0, acc1, 0, 0, 0);
        acc1 = __builtin_amdgcn_mfma_f32_16x16x32_bf16(A1[1], b1, acc1, 0, 0, 0);

        u16 hv0[4], hv1[4];
#pragma unroll
        for (int r = 0; r < 4; r++) {
            float u0 = acc0[r] + g0[r] + g2[r];
            float u1 = acc1[r] + g1[r] + g3[r];
            s0[r] += u0; q0[r] = fmaf(u0, u0, q0[r]);
            s1[r] += u1; q1[r] = fmaf(u1, u1, q1[r]);
            hv0[r] = f2b(u0); hv1[r] = f2b(u1);
        }
        int ge = e0 + ge16;
        u16* hp = h + (long)ge * 128 + j0;
        ushort4 v0 = make_ushort4(hv0[0], hv0[1], hv0[2], hv0[3]);
        ushort4 v1 = make_ushort4(hv1[0], hv1[1], hv1[2], hv1[3]);
        *(ushort4*)hp = v0;
        *(ushort4*)(hp + 64) = v1;
    }

#pragma unroll
    for (int m = 1; m < 16; m <<= 1) {
#pragma unroll
        for (int r = 0; r < 4; r++) {
            s0[r] += __shfl_xor(s0[r], m); q0[r] += __shfl_xor(q0[r], m);
            s1[r] += __shfl_xor(s1[r], m); q1[r] += __shfl_xor(q1[r], m);
        }
    }
    if (n16 == 0) {
        float* sp = spread + (blockIdx.x & (NSPREAD - 1)) * 256;
#pragma unroll
        for (int r = 0; r < 4; r++) {
            atomicAdd(sp + j0 + r,       s0[r]);
            atomicAdd(sp + 128 + j0 + r, q0[r]);
            atomicAdd(sp + 64 + j0 + r,  s1[r]);
            atomicAdd(sp + 192 + j0 + r, q1[r]);
        }
    }
}

// ---------------- t2 fused GEMM pass (fallback) --------------------------------
__global__ __launch_bounds__(256) void k_gemm_h(
    const u16* __restrict__ afb, const float* __restrict__ ea,
    const int* __restrict__ ei, const u16* __restrict__ wT,
    u16* __restrict__ h, float* __restrict__ spread)
{
    __shared__ __align__(16) u16 sTl[64 * 200];
    __shared__ int sSrc[64], sDst[64];
    const int tid = threadIdx.x;
    const int e0 = blockIdx.x * 64;

    if (tid < 64) sSrc[tid] = ei[e0 + tid];
    else if (tid < 128) sDst[tid - 64] = ei[NE + e0 + tid - 64];
    __syncthreads();

    for (int i = tid; i < 1024; i += 256) {
        int e = i >> 4, q = i & 15;
        const u16* g = (q < 8) ? (afb + (long)sSrc[e] * 64 + q * 8)
                               : (afb + (long)sDst[e] * 64 + (q - 8) * 8);
        *(short8*)(sTl + e * 200 + q * 8) = *(const short8*)g;
    }
    for (int i = tid; i < 64 * 64; i += 256) {
        int e = i >> 6, c = i & 63;
        float v = (c < NBRD) ? ea[(long)(e0 + e) * NBRD + c] : 0.f;
        sTl[e * 200 + 128 + c] = f2b(v);
    }
    __syncthreads();

    const int lane = tid & 63, w = tid >> 6;
    const int n16 = lane & 15, quad = lane >> 4;

    short8 A0[6], A1[6];
    {
        const u16* b0 = wT + (16 * w + n16) * 192 + quad * 8;
        const u16* b1 = wT + (16 * (w + 4) + n16) * 192 + quad * 8;
#pragma unroll
        for (int ks = 0; ks < 6; ks++) {
            A0[ks] = *(const short8*)(b0 + ks * 32);
            A1[ks] = *(const short8*)(b1 + ks * 32);
        }
    }

    const int j0 = 16 * w + 4 * quad;
    float s0[4] = {0,0,0,0}, q0[4] = {0,0,0,0}, s1[4] = {0,0,0,0}, q1[4] = {0,0,0,0};

    for (int t = 0; t < 4; t++) {
        const u16* row = sTl + (16 * t + n16) * 200 + quad * 8;
        f32x4 acc0 = {0.f, 0.f, 0.f, 0.f}, acc1 = {0.f, 0.f, 0.f, 0.f};
#pragma unroll
        for (int ks = 0; ks < 6; ks++) {
            short8 b = *(const short8*)(row + ks * 32);
            acc0 = __builtin_amdgcn_mfma_f32_16x16x32_bf16(A0[ks], b, acc0, 0, 0, 0);
            acc1 = __builtin_amdgcn_mfma_f32_16x16x32_bf16(A1[ks], b, acc1, 0, 0, 0);
        }
#pragma unroll
        for (int r = 0; r < 4; r++) {
            s0[r] += acc0[r]; q0[r] = fmaf(acc0[r], acc0[r], q0[r]);
            s1[r] += acc1[r]; q1[r] = fmaf(acc1[r], acc1[r], q1[r]);
        }
        int ge = e0 + 16 * t + n16;
        u16* hp = h + (long)ge * 128 + j0;
        ushort4 v0 = make_ushort4(f2b(acc0[0]), f2b(acc0[1]), f2b(acc0[2]), f2b(acc0[3]));
        ushort4 v1 = make_ushort4(f2b(acc1[0]), f2b(acc1[1]), f2b(acc1[2]), f2b(acc1[3]));
        *(ushort4*)hp = v0;
        *(ushort4*)(hp + 64) = v1;
    }

#pragma unroll
    for (int m = 1; m < 16; m <<= 1) {
#pragma unroll
        for (int r = 0; r < 4; r++) {
            s0[r] += __shfl_xor(s0[r], m); q0[r] += __shfl_xor(q0[r], m);
            s1[r] += __shfl_xor(s1[r], m); q1[r] += __shfl_xor(q1[r], m);
        }
    }
    if (n16 == 0) {
        float* sp = spread + (blockIdx.x & (NSPREAD - 1)) * 256;
#pragma unroll
        for (int r = 0; r < 4; r++) {
            atomicAdd(sp + j0 + r,       s0[r]);
            atomicAdd(sp + 128 + j0 + r, q0[r]);
            atomicAdd(sp + 64 + j0 + r,  s1[r]);
            atomicAdd(sp + 192 + j0 + r, q1[r]);
        }
    }
}

// ---------------- fallback two-pass GEMM (tiny ws) ----------------------------
template <int MODE>
__global__ __launch_bounds__(256) void k_gemm(
    const u16* __restrict__ afb, const float* __restrict__ ea,
    const int* __restrict__ ei, const u16* __restrict__ wT,
    const float* __restrict__ sc, float* __restrict__ outbuf)
{
    __shared__ __align__(16) u16 sTl[64 * 200];
    __shared__ int sSrc[64], sDst[64];
    const int tid = threadIdx.x;
    const int e0 = blockIdx.x * 64;

    if (tid < 64) sSrc[tid] = ei[e0 + tid];
    else if (tid < 128) sDst[tid - 64] = ei[NE + e0 + tid - 64];
    __syncthreads();
    for (int i = tid; i < 1024; i += 256) {
        int e = i >> 4, q = i & 15;
        const u16* g = (q < 8) ? (afb + (long)sSrc[e] * 64 + q * 8)
                               : (afb + (long)sDst[e] * 64 + (q - 8) * 8);
        *(short8*)(sTl + e * 200 + q * 8) = *(const short8*)g;
    }
    for (int i = tid; i < 64 * 64; i += 256) {
        int e = i >> 6, c = i & 63;
        float v = (c < NBRD) ? ea[(long)(e0 + e) * NBRD + c] : 0.f;
        sTl[e * 200 + 128 + c] = f2b(v);
    }
    __syncthreads();

    const int lane = tid & 63, w = tid >> 6;
    const int n16 = lane & 15, quad = lane >> 4;
    short8 A0[6], A1[6];
    {
        const u16* b0 = wT + (16 * w + n16) * 192 + quad * 8;
        const u16* b1 = wT + (16 * (w + 4) + n16) * 192 + quad * 8;
#pragma unroll
        for (int ks = 0; ks < 6; ks++) {
            A0[ks] = *(const short8*)(b0 + ks * 32);
            A1[ks] = *(const short8*)(b1 + ks * 32);
        }
    }
    const int j0 = 16 * w + 4 * quad;
    float s0[4] = {0,0,0,0}, q0[4] = {0,0,0,0}, s1[4] = {0,0,0,0}, q1[4] = {0,0,0,0};
    float scf[4], shf[4], scc[4], shc[4];
    if (MODE == 1) {
#pragma unroll
        for (int r = 0; r < 4; r++) {
            scf[r] = sc[j0 + r];        shf[r] = sc[128 + j0 + r];
            scc[r] = sc[64 + j0 + r];   shc[r] = sc[192 + j0 + r];
        }
    }
    for (int t = 0; t < 4; t++) {
        const u16* row = sTl + (16 * t + n16) * 200 + quad * 8;
        f32x4 acc0 = {0.f, 0.f, 0.f, 0.f}, acc1 = {0.f, 0.f, 0.f, 0.f};
#pragma unroll
        for (int ks = 0; ks < 6; ks++) {
            short8 b = *(const short8*)(row + ks * 32);
            acc0 = __builtin_amdgcn_mfma_f32_16x16x32_bf16(A0[ks], b, acc0, 0, 0, 0);
            acc1 = __builtin_amdgcn_mfma_f32_16x16x32_bf16(A1[ks], b, acc1, 0, 0, 0);
        }
        if (MODE == 0) {
#pragma unroll
            for (int r = 0; r < 4; r++) {
                s0[r] += acc0[r]; q0[r] = fmaf(acc0[r], acc0[r], q0[r]);
                s1[r] += acc1[r]; q1[r] = fmaf(acc1[r], acc1[r], q1[r]);
            }
        } else {
            int src = sSrc[16 * t + n16];
            float* dst = outbuf + (long)src * 64 + j0;
#pragma unroll
            for (int r = 0; r < 4; r++) {
                float f  = fmaf(acc0[r], scf[r], shf[r]);
                float cc = fmaf(acc1[r], scc[r], shc[r]);
                atomicAdd(dst + r, gate(f, cc));
            }
        }
    }
    if (MODE == 0) {
#pragma unroll
        for (int m = 1; m < 16; m <<= 1) {
#pragma unroll
            for (int r = 0; r < 4; r++) {
                s0[r] += __shfl_xor(s0[r], m); q0[r] += __shfl_xor(q0[r], m);
                s1[r] += __shfl_xor(s1[r], m); q1[r] += __shfl_xor(q1[r], m);
            }
        }
        if (n16 == 0) {
            float* sp = outbuf + (blockIdx.x & (NSPREAD - 1)) * 256;
#pragma unroll
            for (int r = 0; r < 4; r++) {
                atomicAdd(sp + j0 + r,       s0[r]);
                atomicAdd(sp + 128 + j0 + r, q0[r]);
                atomicAdd(sp + 64 + j0 + r,  s1[r]);
                atomicAdd(sp + 192 + j0 + r, q1[r]);
            }
        }
    }
}

// ---------------- bn1 finalize (fallback paths) ----------------
__global__ void k_bn1fin(const float* __restrict__ spread,
                         const float* __restrict__ g, const float* __restrict__ b,
                         float* __restrict__ sc)
{
    int c = threadIdx.x;  // 128
    float s = 0.f, q = 0.f;
    for (int k = 0; k < NSPREAD; k++) { s += spread[k * 256 + c]; q += spread[k * 256 + 128 + c]; }
    float mean_acc = s / (float)NE;
    float var = q / (float)NE - mean_acc * mean_acc;
    float scale = g[c] * rsqrtf(var + 1e-5f);
    sc[c] = scale;
    sc[128 + c] = b[c] - mean_acc * scale;
}

// ---------------- t4 gather: per-block bn1 coefs + gate + node sum -------------
__global__ __launch_bounds__(256) void k_scatter3(
    const u16* __restrict__ h, const int* __restrict__ ptr,
    const int* __restrict__ cnt, const float* __restrict__ spread,
    const float* __restrict__ g, const float* __restrict__ b,
    float* __restrict__ summed)
{
    __shared__ float ssc[256];
    int tid = threadIdx.x;
    if (tid < 128) {                       // recompute bn1 coefs (identical to k_bn1fin)
        int c = tid;
        float s = 0.f, q = 0.f;
        for (int k = 0; k < NSPREAD; k++) {
            s += spread[k * 256 + c]; q += spread[k * 256 + 128 + c];
        }
        float mean_acc = s / (float)NE;
        float var = q / (float)NE - mean_acc * mean_acc;
        float scale = g[c] * rsqrtf(var + 1e-5f);
        ssc[c] = scale;
        ssc[128 + c] = b[c] - mean_acc * scale;
    }
    __syncthreads();

    int n = blockIdx.x * 4 + (tid >> 6);
    int l = tid & 63;
    int es = l & 7, cg = l >> 3;

    float scf[8], shf[8], scc[8], shc[8];
#pragma unroll
    for (int j = 0; j < 8; j++) {
        scf[j] = ssc[cg * 8 + j];
        shf[j] = ssc[128 + cg * 8 + j];
        scc[j] = ssc[64 + cg * 8 + j];
        shc[j] = ssc[192 + cg * 8 + j];
    }

    int p0 = ptr[n], deg = cnt[n];
    float acc[8] = {0,0,0,0,0,0,0,0};
    for (int i = 0; i < deg; i += 8) {
        int idx = i + es;
        bool valid = idx < deg;
        int row = p0 + (valid ? idx : 0);
        const u16* hr = h + (long)row * 128;
        short8 f8 = *(const short8*)(hr + cg * 8);
        short8 c8 = *(const short8*)(hr + 64 + cg * 8);
#pragma unroll
        for (int j = 0; j < 8; j++) {
            float f  = fmaf(b2f((u16)f8[j]), scf[j], shf[j]);
            float cc = fmaf(b2f((u16)c8[j]), scc[j], shc[j]);
            float gg = gate(f, cc);
            acc[j] += valid ? gg : 0.f;
        }
    }
#pragma unroll
    for (int m = 1; m < 8; m <<= 1)
#pragma unroll
        for (int j = 0; j < 8; j++) acc[j] += __shfl_xor(acc[j], m);
    if (es == 0) {
        float* sp = summed + (long)n * 64 + cg * 8;
        float4 v0 = {acc[0], acc[1], acc[2], acc[3]};
        float4 v1 = {acc[4], acc[5], acc[6], acc[7]};
        *(float4*)sp = v0;
        *(float4*)(sp + 4) = v1;
    }
}

// ---------------- t3/t2 gather (fallback) --------------------------------------
__global__ __launch_bounds__(256) void k_scatter(
    const u16* __restrict__ h, const int* __restrict__ ptr,
    const int* __restrict__ cnt, const int* __restrict__ eidx,
    const float* __restrict__ sc, float* __restrict__ summed)
{
    int tid = threadIdx.x;
    int n = blockIdx.x * 4 + (tid >> 6);
    int l = tid & 63;
    int es = l & 7, cg = l >> 3;

    float4 a0 = *(const float4*)(sc + cg * 8);
    float4 a1 = *(const float4*)(sc + cg * 8 + 4);
    float4 b0 = *(const float4*)(sc + 128 + cg * 8);
    float4 b1 = *(const float4*)(sc + 128 + cg * 8 + 4);
    float4 c0 = *(const float4*)(sc + 64 + cg * 8);
    float4 c1 = *(const float4*)(sc + 64 + cg * 8 + 4);
    float4 d0 = *(const float4*)(sc + 192 + cg * 8);
    float4 d1 = *(const float4*)(sc + 192 + cg * 8 + 4);
    float scf[8] = {a0.x,a0.y,a0.z,a0.w,a1.x,a1.y,a1.z,a1.w};
    float shf[8] = {b0.x,b0.y,b0.z,b0.w,b1.x,b1.y,b1.z,b1.w};
    float scc[8] = {c0.x,c0.y,c0.z,c0.w,c1.x,c1.y,c1.z,c1.w};
    float shc[8] = {d0.x,d0.y,d0.z,d0.w,d1.x,d1.y,d1.z,d1.w};

    int p0 = ptr[n], deg = cnt[n];
    float acc[8] = {0,0,0,0,0,0,0,0};
    for (int i = 0; i < deg; i += 8) {
        int idx = i + es;
        bool valid = idx < deg;
        int e = eidx[p0 + (valid ? idx : 0)];
        const u16* hr = h + (long)e * 128;
        short8 f8 = *(const short8*)(hr + cg * 8);
        short8 c8 = *(const short8*)(hr + 64 + cg * 8);
#pragma unroll
        for (int j = 0; j < 8; j++) {
            float f  = fmaf(b2f((u16)f8[j]), scf[j], shf[j]);
            float cc = fmaf(b2f((u16)c8[j]), scc[j], shc[j]);
            float gg = gate(f, cc);
            acc[j] += valid ? gg : 0.f;
        }
    }
#pragma unroll
    for (int m = 1; m < 8; m <<= 1)
#pragma unroll
        for (int j = 0; j < 8; j++) acc[j] += __shfl_xor(acc[j], m);
    if (es == 0) {
        float* sp = summed + (long)n * 64 + cg * 8;
        float4 v0 = {acc[0], acc[1], acc[2], acc[3]};
        float4 v1 = {acc[4], acc[5], acc[6], acc[7]};
        *(float4*)sp = v0;
        *(float4*)(sp + 4) = v1;
    }
}

// ---------------- bn2 stats ----------------
__global__ __launch_bounds__(256) void k_bn2stats(const float* __restrict__ summed,
                                                  float* __restrict__ acc2)
{
    int tid = threadIdx.x; int c = tid & 63; int sub = tid >> 6;
    float s = 0.f, q = 0.f;
    for (int r = blockIdx.x * 4 + sub; r < NN; r += 4 * 128) {
        float v = summed[(long)r * 64 + c]; s += v; q = fmaf(v, v, q);
    }
    __shared__ float rs[256], rq[256];
    rs[tid] = s; rq[tid] = q; __syncthreads();
    if (tid < 64) {
        s = rs[tid] + rs[tid + 64] + rs[tid + 128] + rs[tid + 192];
        q = rq[tid] + rq[tid + 64] + rq[tid + 128] + rq[tid + 192];
        atomicAdd(&acc2[tid], s);
        atomicAdd(&acc2[64 + tid], q);
    }
}

// bn2 coefs + out_b init (fallback paths)
__global__ void k_bn2fin(const float* __restrict__ acc2,
                         const float* __restrict__ g, const float* __restrict__ b,
                         float* __restrict__ sc2, const float* __restrict__ outb,
                         float* __restrict__ out)
{
    int c = threadIdx.x;  // 256
    if (c < 64) {
        float mean = acc2[c] / (float)NN;
        float var = acc2[64 + c] / (float)NN - mean * mean;
        float scale = g[c] * rsqrtf(var + 1e-5f);
        sc2[c] = scale;
        sc2[64 + c] = b[c] - mean * scale;
    }
    out[(long)NN * 64 + c] = outb[0];
}

// ---------------- t4: atom_out + silu + logits + segmax, bn2 coefs per block ---
__global__ __launch_bounds__(256) void k_nodepost2(
    const float* __restrict__ summed, const float* __restrict__ acc2,
    const float* __restrict__ g, const float* __restrict__ b,
    const float* __restrict__ attW, const float* __restrict__ attb,
    const int* __restrict__ batch, float* __restrict__ out,
    float* __restrict__ elog, unsigned* __restrict__ segmax)
{
    __shared__ float ssc2[128];
    int tid = threadIdx.x;
    if (tid < 64) {                        // identical to k_bn2fin
        float mean = acc2[tid] / (float)NN;
        float var = acc2[64 + tid] / (float)NN - mean * mean;
        float scale = g[tid] * rsqrtf(var + 1e-5f);
        ssc2[tid] = scale;
        ssc2[64 + tid] = b[tid] - mean * scale;
    }
    __syncthreads();

    int n = blockIdx.x * 4 + (tid >> 6); int c = tid & 63;
    float v = summed[(long)n * 64 + c];
    float ao = fmaf(v, ssc2[c], ssc2[64 + c]);
    out[(long)n * 64 + c] = ao;
    float h = fsilu(ao);
    float p = h * attW[c];
#pragma unroll
    for (int off = 32; off; off >>= 1) p += __shfl_down(p, off, 64);
    if (c == 0) {
        float logit = p + attb[0];
        elog[n] = logit;
        unsigned u = __float_as_uint(logit);
        u = (u & 0x80000000u) ? ~u : (u | 0x80000000u);
        atomicMax(&segmax[batch[n]], u);
    }
}

// fallback nodepost
__global__ __launch_bounds__(256) void k_nodepost(
    const float* __restrict__ summed, const float* __restrict__ sc2,
    const float* __restrict__ attW, const float* __restrict__ attb,
    const int* __restrict__ batch, float* __restrict__ out,
    float* __restrict__ elog, unsigned* __restrict__ segmax)
{
    int tid = threadIdx.x; int n = blockIdx.x * 4 + (tid >> 6); int c = tid & 63;
    float v = summed[(long)n * 64 + c];
    float ao = fmaf(v, sc2[c], sc2[64 + c]);
    out[(long)n * 64 + c] = ao;
    float h = fsilu(ao);
    float p = h * attW[c];
#pragma unroll
    for (int off = 32; off; off >>= 1) p += __shfl_down(p, off, 64);
    if (c == 0) {
        float logit = p + attb[0];
        elog[n] = logit;
        unsigned u = __float_as_uint(logit);
        u = (u & 0x80000000u) ? ~u : (u | 0x80000000u);
        atomicMax(&segmax[batch[n]], u);
    }
}

// t4: denom + crys out_b init
__global__ void k_denom2(const int* __restrict__ batch,
                         const unsigned* __restrict__ segmax,
                         float* __restrict__ elog, float* __restrict__ denom,
                         const float* __restrict__ outb, float* __restrict__ out)
{
    int n = blockIdx.x * 256 + threadIdx.x;
    if (n < NG) out[(long)NN * 64 + n] = outb[0];
    if (n >= NN) return;
    int b = batch[n];
    unsigned u = segmax[b];
    u = (u & 0x80000000u) ? (u & 0x7FFFFFFFu) : ~u;
    float e = __expf(elog[n] - __uint_as_float(u));
    elog[n] = e;
    atomicAdd(&denom[b], e);
}

__global__ void k_denom(const int* __restrict__ batch,
                        const unsigned* __restrict__ segmax,
                        float* __restrict__ elog, float* __restrict__ denom)
{
    int n = blockIdx.x * 256 + threadIdx.x;
    if (n >= NN) return;
    int b = batch[n];
    unsigned u = segmax[b];
    u = (u & 0x80000000u) ? (u & 0x7FFFFFFFu) : ~u;
    float e = __expf(elog[n] - __uint_as_float(u));
    elog[n] = e;
    atomicAdd(&denom[b], e);
}

// weighted pooling fused with out_W projection
__global__ __launch_bounds__(256) void k_crys(
    const float* __restrict__ atom_out, const float* __restrict__ elog,
    const float* __restrict__ denom, const int* __restrict__ batch,
    const float* __restrict__ outW, float* __restrict__ out)
{
    int tid = threadIdx.x; int n = blockIdx.x * 4 + (tid >> 6); int l = tid & 63;
    int b = batch[n];
    float alpha = elog[n] / denom[b];
    float ao = atom_out[(long)n * 64 + l];
    float p = fsilu(ao) * outW[l];
#pragma unroll
    for (int off = 32; off; off >>= 1) p += __shfl_down(p, off, 64);
    if (l == 0) atomicAdd(&out[(long)NN * 64 + b], alpha * p);
}

extern "C" void kernel_launch(void* const* d_in, const int* in_sizes, int n_in,
                              void* d_out, int out_size, void* d_ws, size_t ws_size,
                              hipStream_t stream)
{
    const float* x    = (const float*)d_in[0];
    const float* eatt = (const float*)d_in[1];
    const float* lf   = (const float*)d_in[2];
    const int*   ei   = (const int*)d_in[3];
    const int*   batch= (const int*)d_in[4];
    const float* embW = (const float*)d_in[5];
    const float* embB = (const float*)d_in[6];
    const float* fcW  = (const float*)d_in[7];
    // d_in[8] fc_b folds into bn1 shift
    const float* bn1g = (const float*)d_in[9];
    const float* bn1b = (const float*)d_in[10];
    const float* bn2g = (const float*)d_in[11];
    const float* bn2b = (const float*)d_in[12];
    const float* attW = (const float*)d_in[13];
    const float* attB = (const float*)d_in[14];
    const float* outW = (const float*)d_in[15];
    const float* outB = (const float*)d_in[16];
    float* out = (float*)d_out;
    float* ws  = (float*)d_ws;

    u16* afb  = (u16*)(ws + OFF_AFB);
    u16* wT   = (u16*)(ws + OFF_WT);
    int* cnt  = (int*)(ws + OFF_CNT);
    int* ptr  = (int*)(ws + OFF_PTR);
    int* head = (int*)(ws + OFF_HEAD);
    int* bsum = (int*)(ws + OFF_BSUM);
    int* bofs = (int*)(ws + OFF_BOFS);
    int* eidx = (int*)(ws + OFF_EIDX);
    u16* h    = (u16*)(ws + OFF_H);

    const bool t4 = ws_size >= (size_t)OFF_T4_END * sizeof(float);
    const bool t3 = ws_size >= (size_t)OFF_T3_END * sizeof(float);
    const bool t2 = ws_size >= (size_t)OFF_T2_END * sizeof(float);

    if (t4) {
        u16* wT3  = wT;
        u16* wP   = wT + 8192;
        float* P  = ws + OFF_P;
        int* srcC = (int*)(ws + OFF_SRCC);
        int* dstC = (int*)(ws + OFF_DSTC);
        u16* eaB  = (u16*)(ws + OFF_EAB);
        k_embed2<<<12500, 256, 0, stream>>>(x, lf, embW, embB, afb, fcW, wT3, wP, ws);
        k_hist2<<<(NE * 6 + 255) / 256, 256, 0, stream>>>(ei, eatt, cnt, eaB);
        k_partial<<<(NN + SCAN_B - 1) / SCAN_B, SCAN_B, 0, stream>>>(cnt, ptr, bsum);
        k_scanb<<<1, 256, 0, stream>>>(bsum, bofs, (NN + SCAN_B - 1) / SCAN_B);
        k_addofs<<<(NN + 255) / 256, 256, 0, stream>>>(ptr, bofs, head);
        k_fill2<<<(NE + 255) / 256, 256, 0, stream>>>(ei, head, eidx, srcC, dstC);
        k_pnode<1><<<(NN + 63) / 64, 256, 0, stream>>>(afb, wP, P);
        k_gemm_h5<<<NE / 64, 256, 0, stream>>>(eaB, eidx, srcC, dstC, wT3, P, h,
                                               ws + OFF_BN1SPR);
        k_scatter3<<<NN / 4, 256, 0, stream>>>(h, ptr, cnt, ws + OFF_BN1SPR,
                                               bn1g, bn1b, ws + OFF_SUMMED);
        k_bn2stats<<<128, 256, 0, stream>>>(ws + OFF_SUMMED, ws + OFF_BN2ACC);
        k_nodepost2<<<12500, 256, 0, stream>>>(ws + OFF_SUMMED, ws + OFF_BN2ACC,
                                               bn2g, bn2b, attW, attB, batch, out,
                                               ws + OFF_ELOG,
                                               (unsigned*)(ws + OFF_SEGMAX));
        k_denom2<<<196, 256, 0, stream>>>(batch, (const unsigned*)(ws + OFF_SEGMAX),
                                          ws + OFF_ELOG, ws + OFF_DENOM, outB, out);
        k_crys<<<12500, 256, 0, stream>>>(out, ws + OFF_ELOG, ws + OFF_DENOM, batch,
                                          outW, out);
        return;
    }

    k_embed<<<12500, 256, 0, stream>>>(x, lf, embW, embB, afb);

    if (t3) {
        u16* wT3 = wT;
        u16* wP  = wT + 8192;
        float* P = ws + OFF_P;
        k_prepw2<<<96, 256, 0, stream>>>(fcW, wT3, wP);
        hipMemsetAsync(ws + OFF_BN1SPR, 0,
                       (size_t)(OFF_PTR - OFF_BN1SPR) * sizeof(float), stream);
        k_hist<<<(NE + 255) / 256, 256, 0, stream>>>(ei, cnt);
        k_partial<<<(NN + SCAN_B - 1) / SCAN_B, SCAN_B, 0, stream>>>(cnt, ptr, bsum);
        k_scanb<<<1, 256, 0, stream>>>(bsum, bofs, (NN + SCAN_B - 1) / SCAN_B);
        k_addofs<<<(NN + 255) / 256, 256, 0, stream>>>(ptr, bofs, head);
        k_fill<<<(NE + 255) / 256, 256, 0, stream>>>(ei, head, eidx);
        k_pnode<0><<<(NN + 63) / 64, 256, 0, stream>>>(afb, wP, P);
        k_gemm_h2<<<NE / 64, 256, 0, stream>>>(eatt, ei, wT3, P, h, ws + OFF_BN1SPR);
        k_bn1fin<<<1, 128, 0, stream>>>(ws + OFF_BN1SPR, bn1g, bn1b, ws + OFF_BN1SC);
        k_scatter<<<NN / 4, 256, 0, stream>>>(h, ptr, cnt, eidx, ws + OFF_BN1SC,
                                              ws + OFF_SUMMED);
    } else if (t2) {
        k_prepw<<<96, 256, 0, stream>>>(fcW, wT);
        hipMemsetAsync(ws + OFF_BN1SPR, 0,
                       (size_t)(OFF_PTR - OFF_BN1SPR) * sizeof(float), stream);
        k_hist<<<(NE + 255) / 256, 256, 0, stream>>>(ei, cnt);
        k_partial<<<(NN + SCAN_B - 1) / SCAN_B, SCAN_B, 0, stream>>>(cnt, ptr, bsum);
        k_scanb<<<1, 256, 0, stream>>>(bsum, bofs, (NN + SCAN_B - 1) / SCAN_B);
        k_addofs<<<(NN + 255) / 256, 256, 0, stream>>>(ptr, bofs, head);
        k_fill<<<(NE + 255) / 256, 256, 0, stream>>>(ei, head, eidx);
        k_gemm_h<<<NE / 64, 256, 0, stream>>>(afb, eatt, ei, wT, h, ws + OFF_BN1SPR);
        k_bn1fin<<<1, 128, 0, stream>>>(ws + OFF_BN1SPR, bn1g, bn1b, ws + OFF_BN1SC);
        k_scatter<<<NN / 4, 256, 0, stream>>>(h, ptr, cnt, eidx, ws + OFF_BN1SC,
                                              ws + OFF_SUMMED);
    } else {
        k_prepw<<<96, 256, 0, stream>>>(fcW, wT);
        hipMemsetAsync(ws + OFF_SUMMED, 0,
                       (size_t)(OFF_PTR - OFF_SUMMED) * sizeof(float), stream);
        k_gemm<0><<<NE / 64, 256, 0, stream>>>(afb, eatt, ei, wT, ws + OFF_BN1SC,
                                               ws + OFF_BN1SPR);
        k_bn1fin<<<1, 128, 0, stream>>>(ws + OFF_BN1SPR, bn1g, bn1b, ws + OFF_BN1SC);
        k_gemm<1><<<NE / 64, 256, 0, stream>>>(afb, eatt, ei, wT, ws + OFF_BN1SC,
                                               ws + OFF_SUMMED);
    }

    k_bn2stats<<<128, 256, 0, stream>>>(ws + OFF_SUMMED, ws + OFF_BN2ACC);
    k_bn2fin<<<1, 256, 0, stream>>>(ws + OFF_BN2ACC, bn2g, bn2b, ws + OFF_BN2SC,
                                    outB, out);
    k_nodepost<<<12500, 256, 0, stream>>>(ws + OFF_SUMMED, ws + OFF_BN2SC, attW, attB,
                                          batch, out, ws + OFF_ELOG,
                                          (unsigned*)(ws + OFF_SEGMAX));
    k_denom<<<196, 256, 0, stream>>>(batch, (const unsigned*)(ws + OFF_SEGMAX),
                                     ws + OFF_ELOG, ws + OFF_DENOM);
    k_crys<<<12500, 256, 0, stream>>>(out, ws + OFF_ELOG, ws + OFF_DENOM, batch,
                                      outW, out);
}

// Round 5
// 1154.712 us; speedup vs baseline: 1.1081x; 1.0341x over previous
//
#include <hip/hip_runtime.h>
#include <math.h>

#define NN 50000
#define NE 1000000
#define NG 256
#define ORIGD 92
#define NBRD 41
#define NSPREAD 32
#define SCAN_B 256

typedef unsigned short u16;
typedef __attribute__((ext_vector_type(8))) short short8;   // 8 x bf16 MFMA frag
typedef __attribute__((ext_vector_type(4))) float f32x4;    // MFMA accumulator
typedef __attribute__((ext_vector_type(8))) float f32x8;    // packed P chunk

// ---- workspace layout (float offsets) ----
#define OFF_AFB     0                        // 50000*64 bf16
#define OFF_SUMMED  1600000                  // 50000*64 fp32
#define OFF_WT      4800000                  // t2: 128x192 bf16 | t3/t4: wT3 128x64 + wP 256x64
#define OFF_BN1SPR  4812288                  // 32*256
#define OFF_BN1SC   4820480                  // 256 (fallback paths only)
#define OFF_BN2ACC  4820736                  // 128
#define OFF_BN2SC   4820864                  // 128 (fallback paths only)
#define OFF_ELOG    4820992                  // 50000
#define OFF_SEGMAX  4870992                  // 256
#define OFF_DENOM   4871248                  // 256
#define OFF_CNT     4871504                  // 50000 int
#define OFF_PTR     4921504                  // 50000 int
#define OFF_HEAD    4971504                  // 50000 int
#define OFF_BSUM    5021504                  // 256 int
#define OFF_BOFS    5021760                  // 256 int
#define OFF_EIDX    5022016                  // 1M int (edge id per CSR position)
#define OFF_H       6022016                  // 1M*128 bf16 (256 MB)
#define OFF_T2_END  70022016
#define OFF_P       70022016                 // t3: 50000*256 fp32 | t4: P1 50000*128 fp32
#define OFF_P2      76422016                 // t4: 50000*128 bf16 (3.2M floats)
#define OFF_T3_END  82822016
#define OFF_SRCC    82822016                 // t4: 1M int src in CSR order
#define OFF_DSTC    83822016                 // t4: 1M int dst in CSR order
#define OFF_EAB     84822016                 // t4: 1M*48 bf16 edge_attr (EDGE order)
#define OFF_T4_END  108822016

__device__ __forceinline__ u16 f2b(float f) {          // fp32 -> bf16 RNE
    unsigned u = __float_as_uint(f);
    return (u16)((u + 0x7FFFu + ((u >> 16) & 1u)) >> 16);
}
__device__ __forceinline__ float b2f(u16 u) {
    return __uint_as_float(((unsigned)u) << 16);
}
__device__ __forceinline__ float gate(float f, float cc) {
    float sig = __builtin_amdgcn_rcpf(1.f + __expf(-f));
    float sp  = fmaxf(cc, 0.f) + __logf(1.f + __expf(-fabsf(cc)));
    return sig * sp;
}
__device__ __forceinline__ float fsilu(float x) {
    return x * __builtin_amdgcn_rcpf(1.f + __expf(-x));
}

// ---------------- t4 mega-prolog: embed + weight prep + workspace zeroing ------
__global__ __launch_bounds__(256) void k_embed2(
    const float* __restrict__ x, const float* __restrict__ lf,
    const float* __restrict__ W, const float* __restrict__ b,
    u16* __restrict__ afb, const float* __restrict__ fcW,
    u16* __restrict__ wT3, u16* __restrict__ wP, float* __restrict__ ws)
{
    int gid = blockIdx.x * 256 + threadIdx.x;
    int n = gid >> 6, c = gid & 63;
    const float* xr = x + (long)n * ORIGD;
    float acc = b[c] + lf[gid];
#pragma unroll 4
    for (int k = 0; k < ORIGD; k++)
        acc = fmaf(xr[k], W[k * 64 + c], acc);
    afb[gid] = f2b(acc);

    if (blockIdx.x < 96) {                      // prepw2 work
        int i = blockIdx.x * 256 + threadIdx.x; // 24576 = 8192 + 16384
        if (i < 8192) {
            int j = i >> 6, k = i & 63;
            wT3[i] = (k < NBRD) ? f2b(fcW[(128 + k) * 128 + j]) : (u16)0;
        } else {
            int i2 = i - 8192;
            int j = i2 >> 6, k = i2 & 63;
            int row = (j < 128) ? k : (64 + k);
            wP[i2] = f2b(fcW[row * 128 + (j & 127)]);
        }
    } else if (blockIdx.x < 336) {              // zeroing work
        int zid = (blockIdx.x - 96) * 256 + threadIdx.x;
        if (zid < 8704) {
            ws[OFF_BN1SPR + zid] = 0.f;
        } else {
            int z2 = zid - 8704;
            if (z2 < 50512) ws[OFF_SEGMAX + z2] = 0.f;
        }
    }
}

// ---------------- prep (t2 path) ----
__global__ void k_prepw(const float* __restrict__ fcW, u16* __restrict__ wT)
{
    int i = blockIdx.x * 256 + threadIdx.x;        // 24576
    int j = i / 192, k = i - j * 192;
    wT[i] = (k < 169) ? f2b(fcW[k * 128 + j]) : (u16)0;
}

// ---------------- prep (t3 fallback) ----
__global__ void k_prepw2(const float* __restrict__ fcW, u16* __restrict__ wT3,
                         u16* __restrict__ wP)
{
    int i = blockIdx.x * 256 + threadIdx.x;
    if (i < 8192) {
        int j = i >> 6, k = i & 63;
        wT3[i] = (k < NBRD) ? f2b(fcW[(128 + k) * 128 + j]) : (u16)0;
    } else {
        int i2 = i - 8192;
        int j = i2 >> 6, k = i2 & 63;
        int row = (j < 128) ? k : (64 + k);
        wP[i2] = f2b(fcW[row * 128 + (j & 127)]);
    }
}

// ---------------- t2/t3 fallback embed ----
__global__ __launch_bounds__(256) void k_embed(
    const float* __restrict__ x, const float* __restrict__ lf,
    const float* __restrict__ W, const float* __restrict__ b,
    u16* __restrict__ afb)
{
    int gid = blockIdx.x * 256 + threadIdx.x;
    int n = gid >> 6, c = gid & 63;
    const float* xr = x + (long)n * ORIGD;
    float acc = b[c] + lf[gid];
#pragma unroll 4
    for (int k = 0; k < ORIGD; k++)
        acc = fmaf(xr[k], W[k * 64 + c], acc);
    afb[gid] = f2b(acc);
}

// ---------------- node pre-projection (t3 fallback, plain layout) --------------
__global__ __launch_bounds__(256) void k_pnode(
    const u16* __restrict__ afb, const u16* __restrict__ wP, float* __restrict__ P)
{
    __shared__ __align__(16) u16 sB[64 * 72];
    const int tid = threadIdx.x;
    const int n0 = blockIdx.x * 64;

    for (int i = tid; i < 512; i += 256) {
        int r = i >> 3, c = i & 7;
        int n = n0 + r;
        short8 v = {0,0,0,0,0,0,0,0};
        if (n < NN) v = *(const short8*)(afb + (long)n * 64 + c * 8);
        *(short8*)(sB + r * 72 + c * 8) = v;
    }
    __syncthreads();

    const int lane = tid & 63, w = tid >> 6;
    const int n16 = lane & 15, quad = lane >> 4;
    short8 A[4][2];
#pragma unroll
    for (int m = 0; m < 4; m++) {
        const u16* base = wP + (16 * (w + 4 * m) + n16) * 64 + quad * 8;
        A[m][0] = *(const short8*)(base);
        A[m][1] = *(const short8*)(base + 32);
    }
    for (int t = 0; t < 4; t++) {
        const u16* row = sB + (16 * t + n16) * 72 + quad * 8;
        short8 b0 = *(const short8*)(row);
        short8 b1 = *(const short8*)(row + 32);
        int n = n0 + 16 * t + n16;
#pragma unroll
        for (int m = 0; m < 4; m++) {
            f32x4 acc = {0.f, 0.f, 0.f, 0.f};
            acc = __builtin_amdgcn_mfma_f32_16x16x32_bf16(A[m][0], b0, acc, 0, 0, 0);
            acc = __builtin_amdgcn_mfma_f32_16x16x32_bf16(A[m][1], b1, acc, 0, 0, 0);
            if (n < NN) {
                int j = 16 * (w + 4 * m) + 4 * quad;
                *(f32x4*)(P + (long)n * 256 + j) = acc;
            }
        }
    }
}

// ---------------- t4 node pre-projection: split P1 fp32 / P2 bf16, packed ------
// P1[n][128] fp32: chunk (w*4+quad)*8 holds {P1[j0..j0+3], P1[64+j0..64+j0+3]}
// P2[n][128] bf16: same packing of the dst-half (fc cols 128..255)
__global__ __launch_bounds__(256) void k_pnodeS(
    const u16* __restrict__ afb, const u16* __restrict__ wP,
    float* __restrict__ P1, u16* __restrict__ P2)
{
    __shared__ __align__(16) u16 sB[64 * 72];
    const int tid = threadIdx.x;
    const int n0 = blockIdx.x * 64;

    for (int i = tid; i < 512; i += 256) {
        int r = i >> 3, c = i & 7;
        int n = n0 + r;
        short8 v = {0,0,0,0,0,0,0,0};
        if (n < NN) v = *(const short8*)(afb + (long)n * 64 + c * 8);
        *(short8*)(sB + r * 72 + c * 8) = v;
    }
    __syncthreads();

    const int lane = tid & 63, w = tid >> 6;
    const int n16 = lane & 15, quad = lane >> 4;
    short8 A[4][2];
#pragma unroll
    for (int m = 0; m < 4; m++) {
        const u16* base = wP + (16 * (w + 4 * m) + n16) * 64 + quad * 8;
        A[m][0] = *(const short8*)(base);
        A[m][1] = *(const short8*)(base + 32);
    }
    for (int t = 0; t < 4; t++) {
        const u16* row = sB + (16 * t + n16) * 72 + quad * 8;
        short8 b0 = *(const short8*)(row);
        short8 b1 = *(const short8*)(row + 32);
        int n = n0 + 16 * t + n16;
#pragma unroll
        for (int m = 0; m < 4; m++) {
            f32x4 acc = {0.f, 0.f, 0.f, 0.f};
            acc = __builtin_amdgcn_mfma_f32_16x16x32_bf16(A[m][0], b0, acc, 0, 0, 0);
            acc = __builtin_amdgcn_mfma_f32_16x16x32_bf16(A[m][1], b1, acc, 0, 0, 0);
            if (n < NN) {
                int M = w + 4 * m;
                int MM = M & 7;
                int inner = ((MM & 3) * 4 + quad) * 8 + ((MM >> 2) << 2);
                if (M < 8) {
                    *(f32x4*)(P1 + (long)n * 128 + inner) = acc;
                } else {
                    ushort4 v = make_ushort4(f2b(acc[0]), f2b(acc[1]),
                                             f2b(acc[2]), f2b(acc[3]));
                    *(ushort4*)(P2 + (long)n * 128 + inner) = v;
                }
            }
        }
    }
}

// ---------------- CSR build ----------------
__global__ void k_hist(const int* __restrict__ ei, int* __restrict__ cnt)
{
    int e = blockIdx.x * 256 + threadIdx.x;
    if (e < NE) atomicAdd(&cnt[ei[e]], 1);
}

// t4: hist fused with ea->bf16 conversion in EDGE order (coalesced both sides).
__global__ __launch_bounds__(256) void k_hist2(
    const int* __restrict__ ei, const float* __restrict__ ea,
    int* __restrict__ cnt, u16* __restrict__ eaB)
{
    long gid = (long)blockIdx.x * 256 + threadIdx.x;
    if (gid >= (long)NE * 6) return;
    int e = (int)(gid / 6);
    int q = (int)(gid - (long)e * 6);
    if (q == 0) atomicAdd(&cnt[ei[e]], 1);
    const float* row = ea + (long)e * NBRD;
    int c0 = q * 8;
    short8 v;
#pragma unroll
    for (int j = 0; j < 8; j++) {
        int c = c0 + j;
        v[j] = (c < NBRD) ? (short)f2b(row[c]) : (short)0;
    }
    *(short8*)(eaB + (long)e * 48 + c0) = v;
}

// parallel scan
__global__ void k_partial(const int* __restrict__ cnt, int* __restrict__ lofs,
                          int* __restrict__ bsum)
{
    __shared__ int sd[SCAN_B];
    int t = threadIdx.x, b = blockIdx.x, n = b * SCAN_B + t;
    int v = (n < NN) ? cnt[n] : 0;
    sd[t] = v; __syncthreads();
    for (int o = 1; o < SCAN_B; o <<= 1) {
        int x = (t >= o) ? sd[t - o] : 0;
        __syncthreads();
        sd[t] += x;
        __syncthreads();
    }
    if (n < NN) lofs[n] = sd[t] - v;
    if (t == SCAN_B - 1) bsum[b] = sd[t];
}

__global__ void k_scanb(const int* __restrict__ bsum, int* __restrict__ bofs, int nb)
{
    __shared__ int sd[256];
    int t = threadIdx.x;
    int v = (t < nb) ? bsum[t] : 0;
    sd[t] = v; __syncthreads();
    for (int o = 1; o < 256; o <<= 1) {
        int x = (t >= o) ? sd[t - o] : 0;
        __syncthreads();
        sd[t] += x;
        __syncthreads();
    }
    bofs[t] = sd[t] - v;
}

__global__ void k_addofs(int* __restrict__ ptr, const int* __restrict__ bofs,
                         int* __restrict__ head)
{
    int n = blockIdx.x * 256 + threadIdx.x;
    if (n < NN) {
        int p = ptr[n] + bofs[n >> 8];
        ptr[n] = p; head[n] = p;
    }
}

__global__ void k_fill(const int* __restrict__ ei, int* __restrict__ head,
                       int* __restrict__ eidx)
{
    int e = blockIdx.x * 256 + threadIdx.x;
    if (e < NE) {
        int pos = atomicAdd(&head[ei[e]], 1);
        eidx[pos] = e;
    }
}

// t4: CSR fill, 4-B scattered writes only
__global__ void k_fill2(const int* __restrict__ ei, int* __restrict__ head,
                        int* __restrict__ eidx, int* __restrict__ srcC,
                        int* __restrict__ dstC)
{
    int e = blockIdx.x * 256 + threadIdx.x;
    if (e < NE) {
        int s = ei[e];
        int pos = atomicAdd(&head[s], 1);
        eidx[pos] = e;
        srcC[pos] = s;
        dstC[pos] = ei[NE + e];
    }
}

// ---------------- t4 edge pass: CSR order, P1 fp32 + P2 bf16, pair-packed h ----
__global__ __launch_bounds__(256) void k_gemm_h6(
    const u16* __restrict__ eaB, const int* __restrict__ eidx,
    const int* __restrict__ srcC, const int* __restrict__ dstC,
    const u16* __restrict__ wT3, const float* __restrict__ P1,
    const u16* __restrict__ P2, u16* __restrict__ h,
    float* __restrict__ spread)
{
    const int tid = threadIdx.x;
    const int e0 = blockIdx.x * 64;
    const int lane = tid & 63, w = tid >> 6;
    const int n16 = lane & 15, quad = lane >> 4;

    short8 A0[2], A1[2];
    {
        const u16* a0 = wT3 + (16 * w + n16) * 64 + quad * 8;
        const u16* a1 = wT3 + (16 * (w + 4) + n16) * 64 + quad * 8;
        A0[0] = *(const short8*)(a0);  A0[1] = *(const short8*)(a0 + 32);
        A1[0] = *(const short8*)(a1);  A1[1] = *(const short8*)(a1 + 32);
    }

    const int j0 = 16 * w + 4 * quad;
    const int pofs = (w * 4 + quad) * 8;
    const short8 bz = {0,0,0,0,0,0,0,0};
    float s0[4] = {0,0,0,0}, q0[4] = {0,0,0,0}, s1[4] = {0,0,0,0}, q1[4] = {0,0,0,0};

#pragma unroll
    for (int t = 0; t < 4; t++) {
        const int pos = e0 + 16 * t + n16;
        const int src = srcC[pos];
        const int dst = dstC[pos];
        const int e   = eidx[pos];

        const u16* er = eaB + (long)e * 48;
        short8 b0 = *(const short8*)(er + quad * 8);
        short8 b1 = (quad < 2) ? *(const short8*)(er + 32 + quad * 8) : bz;

        // node contributions: P1 fp32 (CSR L1-hot), P2 bf16 (L2-resident random)
        f32x8 gS = *(const f32x8*)(P1 + (long)src * 128 + pofs);
        short8 gDb = *(const short8*)(P2 + (long)dst * 128 + pofs);

        f32x4 acc0 = {0.f, 0.f, 0.f, 0.f}, acc1 = {0.f, 0.f, 0.f, 0.f};
        acc0 = __builtin_amdgcn_mfma_f32_16x16x32_bf16(A0[0], b0, acc0, 0, 0, 0);
        acc0 = __builtin_amdgcn_mfma_f32_16x16x32_bf16(A0[1], b1, acc0, 0, 0, 0);
        acc1 = __builtin_amdgcn_mfma_f32_16x16x32_bf16(A1[0], b0, acc1, 0, 0, 0);
        acc1 = __builtin_amdgcn_mfma_f32_16x16x32_bf16(A1[1], b1, acc1, 0, 0, 0);

        u16 hv0[4], hv1[4];
#pragma unroll
        for (int r = 0; r < 4; r++) {
            float u0 = acc0[r] + gS[r]     + b2f((u16)gDb[r]);
            float u1 = acc1[r] + gS[4 + r] + b2f((u16)gDb[4 + r]);
            s0[r] += u0; q0[r] = fmaf(u0, u0, q0[r]);
            s1[r] += u1; q1[r] = fmaf(u1, u1, q1[r]);
            hv0[r] = f2b(u0); hv1[r] = f2b(u1);
        }
        // pair-packed h: [pos][j]{filter,core}; lane's 4 pairs = one 16 B store
        short8 hv;
        hv[0] = (short)hv0[0]; hv[1] = (short)hv1[0];
        hv[2] = (short)hv0[1]; hv[3] = (short)hv1[1];
        hv[4] = (short)hv0[2]; hv[5] = (short)hv1[2];
        hv[6] = (short)hv0[3]; hv[7] = (short)hv1[3];
        *(short8*)(h + (long)pos * 128 + j0 * 2) = hv;
    }

#pragma unroll
    for (int m = 1; m < 16; m <<= 1) {
#pragma unroll
        for (int r = 0; r < 4; r++) {
            s0[r] += __shfl_xor(s0[r], m); q0[r] += __shfl_xor(q0[r], m);
            s1[r] += __shfl_xor(s1[r], m); q1[r] += __shfl_xor(q1[r], m);
        }
    }
    if (n16 == 0) {
        float* sp = spread + (blockIdx.x & (NSPREAD - 1)) * 256;
#pragma unroll
        for (int r = 0; r < 4; r++) {
            atomicAdd(sp + j0 + r,       s0[r]);
            atomicAdd(sp + 128 + j0 + r, q0[r]);
            atomicAdd(sp + 64 + j0 + r,  s1[r]);
            atomicAdd(sp + 192 + j0 + r, q1[r]);
        }
    }
}

// ---------------- t3 edge pass (fallback) -------------------------------------
__global__ __launch_bounds__(256) void k_gemm_h2(
    const float* __restrict__ ea, const int* __restrict__ ei,
    const u16* __restrict__ wT3, const float* __restrict__ P,
    u16* __restrict__ h, float* __restrict__ spread)
{
    __shared__ __align__(16) u16 sTl[64 * 72];
    __shared__ int sSrc[64], sDst[64];
    const int tid = threadIdx.x;
    const int e0 = blockIdx.x * 64;

    if (tid < 64) sSrc[tid] = ei[e0 + tid];
    else if (tid < 128) sDst[tid - 64] = ei[NE + e0 + tid - 64];

    for (int i = tid; i < 64 * 64; i += 256) {
        int e = i >> 6, c = i & 63;
        float v = (c < NBRD) ? ea[(long)(e0 + e) * NBRD + c] : 0.f;
        sTl[e * 72 + c] = f2b(v);
    }
    __syncthreads();

    const int lane = tid & 63, w = tid >> 6;
    const int n16 = lane & 15, quad = lane >> 4;

    short8 A0[2], A1[2];
    {
        const u16* b0 = wT3 + (16 * w + n16) * 64 + quad * 8;
        const u16* b1 = wT3 + (16 * (w + 4) + n16) * 64 + quad * 8;
        A0[0] = *(const short8*)(b0);  A0[1] = *(const short8*)(b0 + 32);
        A1[0] = *(const short8*)(b1);  A1[1] = *(const short8*)(b1 + 32);
    }

    const int j0 = 16 * w + 4 * quad;
    float s0[4] = {0,0,0,0}, q0[4] = {0,0,0,0}, s1[4] = {0,0,0,0}, q1[4] = {0,0,0,0};

    for (int t = 0; t < 4; t++) {
        const int ge16 = 16 * t + n16;
        const int src = sSrc[ge16], dst = sDst[ge16];
        const float* pS = P + (long)src * 256;
        const float* pD = P + (long)dst * 256 + 128;
        f32x4 g0 = *(const f32x4*)(pS + j0);
        f32x4 g1 = *(const f32x4*)(pS + 64 + j0);
        f32x4 g2 = *(const f32x4*)(pD + j0);
        f32x4 g3 = *(const f32x4*)(pD + 64 + j0);

        const u16* row = sTl + ge16 * 72 + quad * 8;
        short8 b0 = *(const short8*)(row);
        short8 b1 = *(const short8*)(row + 32);
        f32x4 acc0 = {0.f, 0.f, 0.f, 0.f}, acc1 = {0.f, 0.f, 0.f, 0.f};
        acc0 = __builtin_amdgcn_mfma_f32_16x16x32_bf16(A0[0], b0, acc0, 0, 0, 0);
        acc0 = __builtin_amdgcn_mfma_f32_16x16x32_bf16(A0[1], b1, acc0, 0, 0, 0);
        acc1 = __builtin_amdgcn_mfma_f32_16x16x32_bf16(A1[0], b0, acc1, 0, 0, 0);
        acc1 = __builtin_amdgcn_mfma_f32_16x16x32_bf16(A1[1], b1, acc1, 0, 0, 0);

        u16 hv0[4], hv1[4];
#pragma unroll
        for (int r = 0; r < 4; r++) {
            float u0 = acc0[r] + g0[r] + g2[r];
            float u1 = acc1[r] + g1[r] + g3[r];
            s0[r] += u0; q0[r] = fmaf(u0, u0, q0[r]);
            s1[r] += u1; q1[r] = fmaf(u1, u1, q1[r]);
            hv0[r] = f2b(u0); hv1[r] = f2b(u1);
        }
        int ge = e0 + ge16;
        u16* hp = h + (long)ge * 128 + j0;
        ushort4 v0 = make_ushort4(hv0[0], hv0[1], hv0[2], hv0[3]);
        ushort4 v1 = make_ushort4(hv1[0], hv1[1], hv1[2], hv1[3]);
        *(ushort4*)hp = v0;
        *(ushort4*)(hp + 64) = v1;
    }

#pragma unroll
    for (int m = 1; m < 16; m <<= 1) {
#pragma unroll
        for (int r = 0; r < 4; r++) {
            s0[r] += __shfl_xor(s0[r], m); q0[r] += __shfl_xor(q0[r], m);
            s1[r] += __shfl_xor(s1[r], m); q1[r] += __shfl_xor(q1[r], m);
        }
    }
    if (n16 == 0) {
        float* sp = spread + (blockIdx.x & (NSPREAD - 1)) * 256;
#pragma unroll
        for (int r = 0; r < 4; r++) {
            atomicAdd(sp + j0 + r,       s0[r]);
            atomicAdd(sp + 128 + j0 + r, q0[r]);
            atomicAdd(sp + 64 + j0 + r,  s1[r]);
            atomicAdd(sp + 192 + j0 + r, q1[r]);
        }
    }
}

// ---------------- t2 fused GEMM pass (fallback) --------------------------------
__global__ __launch_bounds__(256) void k_gemm_h(
    const u16* __restrict__ afb, const float* __restrict__ ea,
    const int* __restrict__ ei, const u16* __restrict__ wT,
    u16* __restrict__ h, float* __restrict__ spread)
{
    __shared__ __align__(16) u16 sTl[64 * 200];
    __shared__ int sSrc[64], sDst[64];
    const int tid = threadIdx.x;
    const int e0 = blockIdx.x * 64;

    if (tid < 64) sSrc[tid] = ei[e0 + tid];
    else if (tid < 128) sDst[tid - 64] = ei[NE + e0 + tid - 64];
    __syncthreads();

    for (int i = tid; i < 1024; i += 256) {
        int e = i >> 4, q = i & 15;
        const u16* g = (q < 8) ? (afb + (long)sSrc[e] * 64 + q * 8)
                               : (afb + (long)sDst[e] * 64 + (q - 8) * 8);
        *(short8*)(sTl + e * 200 + q * 8) = *(const short8*)g;
    }
    for (int i = tid; i < 64 * 64; i += 256) {
        int e = i >> 6, c = i & 63;
        float v = (c < NBRD) ? ea[(long)(e0 + e) * NBRD + c] : 0.f;
        sTl[e * 200 + 128 + c] = f2b(v);
    }
    __syncthreads();

    const int lane = tid & 63, w = tid >> 6;
    const int n16 = lane & 15, quad = lane >> 4;

    short8 A0[6], A1[6];
    {
        const u16* b0 = wT + (16 * w + n16) * 192 + quad * 8;
        const u16* b1 = wT + (16 * (w + 4) + n16) * 192 + quad * 8;
#pragma unroll
        for (int ks = 0; ks < 6; ks++) {
            A0[ks] = *(const short8*)(b0 + ks * 32);
            A1[ks] = *(const short8*)(b1 + ks * 32);
        }
    }

    const int j0 = 16 * w + 4 * quad;
    float s0[4] = {0,0,0,0}, q0[4] = {0,0,0,0}, s1[4] = {0,0,0,0}, q1[4] = {0,0,0,0};

    for (int t = 0; t < 4; t++) {
        const u16* row = sTl + (16 * t + n16) * 200 + quad * 8;
        f32x4 acc0 = {0.f, 0.f, 0.f, 0.f}, acc1 = {0.f, 0.f, 0.f, 0.f};
#pragma unroll
        for (int ks = 0; ks < 6; ks++) {
            short8 b = *(const short8*)(row + ks * 32);
            acc0 = __builtin_amdgcn_mfma_f32_16x16x32_bf16(A0[ks], b, acc0, 0, 0, 0);
            acc1 = __builtin_amdgcn_mfma_f32_16x16x32_bf16(A1[ks], b, acc1, 0, 0, 0);
        }
#pragma unroll
        for (int r = 0; r < 4; r++) {
            s0[r] += acc0[r]; q0[r] = fmaf(acc0[r], acc0[r], q0[r]);
            s1[r] += acc1[r]; q1[r] = fmaf(acc1[r], acc1[r], q1[r]);
        }
        int ge = e0 + 16 * t + n16;
        u16* hp = h + (long)ge * 128 + j0;
        ushort4 v0 = make_ushort4(f2b(acc0[0]), f2b(acc0[1]), f2b(acc0[2]), f2b(acc0[3]));
        ushort4 v1 = make_ushort4(f2b(acc1[0]), f2b(acc1[1]), f2b(acc1[2]), f2b(acc1[3]));
        *(ushort4*)hp = v0;
        *(ushort4*)(hp + 64) = v1;
    }

#pragma unroll
    for (int m = 1; m < 16; m <<= 1) {
#pragma unroll
        for (int r = 0; r < 4; r++) {
            s0[r] += __shfl_xor(s0[r], m); q0[r] += __shfl_xor(q0[r], m);
            s1[r] += __shfl_xor(s1[r], m); q1[r] += __shfl_xor(q1[r], m);
        }
    }
    if (n16 == 0) {
        float* sp = spread + (blockIdx.x & (NSPREAD - 1)) * 256;
#pragma unroll
        for (int r = 0; r < 4; r++) {
            atomicAdd(sp + j0 + r,       s0[r]);
            atomicAdd(sp + 128 + j0 + r, q0[r]);
            atomicAdd(sp + 64 + j0 + r,  s1[r]);
            atomicAdd(sp + 192 + j0 + r, q1[r]);
        }
    }
}

// ---------------- fallback two-pass GEMM (tiny ws) ----------------------------
template <int MODE>
__global__ __launch_bounds__(256) void k_gemm(
    const u16* __restrict__ afb, const float* __restrict__ ea,
    const int* __restrict__ ei, const u16* __restrict__ wT,
    const float* __restrict__ sc, float* __restrict__ outbuf)
{
    __shared__ __align__(16) u16 sTl[64 * 200];
    __shared__ int sSrc[64], sDst[64];
    const int tid = threadIdx.x;
    const int e0 = blockIdx.x * 64;

    if (tid < 64) sSrc[tid] = ei[e0 + tid];
    else if (tid < 128) sDst[tid - 64] = ei[NE + e0 + tid - 64];
    __syncthreads();
    for (int i = tid; i < 1024; i += 256) {
        int e = i >> 4, q = i & 15;
        const u16* g = (q < 8) ? (afb + (long)sSrc[e] * 64 + q * 8)
                               : (afb + (long)sDst[e] * 64 + (q - 8) * 8);
        *(short8*)(sTl + e * 200 + q * 8) = *(const short8*)g;
    }
    for (int i = tid; i < 64 * 64; i += 256) {
        int e = i >> 6, c = i & 63;
        float v = (c < NBRD) ? ea[(long)(e0 + e) * NBRD + c] : 0.f;
        sTl[e * 200 + 128 + c] = f2b(v);
    }
    __syncthreads();

    const int lane = tid & 63, w = tid >> 6;
    const int n16 = lane & 15, quad = lane >> 4;
    short8 A0[6], A1[6];
    {
        const u16* b0 = wT + (16 * w + n16) * 192 + quad * 8;
        const u16* b1 = wT + (16 * (w + 4) + n16) * 192 + quad * 8;
#pragma unroll
        for (int ks = 0; ks < 6; ks++) {
            A0[ks] = *(const short8*)(b0 + ks * 32);
            A1[ks] = *(const short8*)(b1 + ks * 32);
        }
    }
    const int j0 = 16 * w + 4 * quad;
    float s0[4] = {0,0,0,0}, q0[4] = {0,0,0,0}, s1[4] = {0,0,0,0}, q1[4] = {0,0,0,0};
    float scf[4], shf[4], scc[4], shc[4];
    if (MODE == 1) {
#pragma unroll
        for (int r = 0; r < 4; r++) {
            scf[r] = sc[j0 + r];        shf[r] = sc[128 + j0 + r];
            scc[r] = sc[64 + j0 + r];   shc[r] = sc[192 + j0 + r];
        }
    }
    for (int t = 0; t < 4; t++) {
        const u16* row = sTl + (16 * t + n16) * 200 + quad * 8;
        f32x4 acc0 = {0.f, 0.f, 0.f, 0.f}, acc1 = {0.f, 0.f, 0.f, 0.f};
#pragma unroll
        for (int ks = 0; ks < 6; ks++) {
            short8 b = *(const short8*)(row + ks * 32);
            acc0 = __builtin_amdgcn_mfma_f32_16x16x32_bf16(A0[ks], b, acc0, 0, 0, 0);
            acc1 = __builtin_amdgcn_mfma_f32_16x16x32_bf16(A1[ks], b, acc1, 0, 0, 0);
        }
        if (MODE == 0) {
#pragma unroll
            for (int r = 0; r < 4; r++) {
                s0[r] += acc0[r]; q0[r] = fmaf(acc0[r], acc0[r], q0[r]);
                s1[r] += acc1[r]; q1[r] = fmaf(acc1[r], acc1[r], q1[r]);
            }
        } else {
            int src = sSrc[16 * t + n16];
            float* dst = outbuf + (long)src * 64 + j0;
#pragma unroll
            for (int r = 0; r < 4; r++) {
                float f  = fmaf(acc0[r], scf[r], shf[r]);
                float cc = fmaf(acc1[r], scc[r], shc[r]);
                atomicAdd(dst + r, gate(f, cc));
            }
        }
    }
    if (MODE == 0) {
#pragma unroll
        for (int m = 1; m < 16; m <<= 1) {
#pragma unroll
            for (int r = 0; r < 4; r++) {
                s0[r] += __shfl_xor(s0[r], m); q0[r] += __shfl_xor(q0[r], m);
                s1[r] += __shfl_xor(s1[r], m); q1[r] += __shfl_xor(q1[r], m);
            }
        }
        if (n16 == 0) {
            float* sp = outbuf + (blockIdx.x & (NSPREAD - 1)) * 256;
#pragma unroll
            for (int r = 0; r < 4; r++) {
                atomicAdd(sp + j0 + r,       s0[r]);
                atomicAdd(sp + 128 + j0 + r, q0[r]);
                atomicAdd(sp + 64 + j0 + r,  s1[r]);
                atomicAdd(sp + 192 + j0 + r, q1[r]);
            }
        }
    }
}

// ---------------- bn1 finalize (fallback paths) ----------------
__global__ void k_bn1fin(const float* __restrict__ spread,
                         const float* __restrict__ g, const float* __restrict__ b,
                         float* __restrict__ sc)
{
    int c = threadIdx.x;  // 128
    float s = 0.f, q = 0.f;
    for (int k = 0; k < NSPREAD; k++) { s += spread[k * 256 + c]; q += spread[k * 256 + 128 + c]; }
    float mean_acc = s / (float)NE;
    float var = q / (float)NE - mean_acc * mean_acc;
    float scale = g[c] * rsqrtf(var + 1e-5f);
    sc[c] = scale;
    sc[128 + c] = b[c] - mean_acc * scale;
}

// ---------------- t4 gather: per-block bn1 coefs + gate + node sum -------------
// h is pair-packed: [pos][j]{filter,core}; lane reads one 32 B contiguous chunk.
__global__ __launch_bounds__(256) void k_scatter4(
    const u16* __restrict__ h, const int* __restrict__ ptr,
    const int* __restrict__ cnt, const float* __restrict__ spread,
    const float* __restrict__ g, const float* __restrict__ b,
    float* __restrict__ summed)
{
    __shared__ float ssc[256];
    int tid = threadIdx.x;
    if (tid < 128) {                       // recompute bn1 coefs (identical to k_bn1fin)
        int c = tid;
        float s = 0.f, q = 0.f;
        for (int k = 0; k < NSPREAD; k++) {
            s += spread[k * 256 + c]; q += spread[k * 256 + 128 + c];
        }
        float mean_acc = s / (float)NE;
        float var = q / (float)NE - mean_acc * mean_acc;
        float scale = g[c] * rsqrtf(var + 1e-5f);
        ssc[c] = scale;
        ssc[128 + c] = b[c] - mean_acc * scale;
    }
    __syncthreads();

    int n = blockIdx.x * 4 + (tid >> 6);
    int l = tid & 63;
    int es = l & 7, cg = l >> 3;

    float scf[8], shf[8], scc[8], shc[8];
#pragma unroll
    for (int j = 0; j < 8; j++) {
        scf[j] = ssc[cg * 8 + j];
        shf[j] = ssc[128 + cg * 8 + j];
        scc[j] = ssc[64 + cg * 8 + j];
        shc[j] = ssc[192 + cg * 8 + j];
    }

    int p0 = ptr[n], deg = cnt[n];
    float acc[8] = {0,0,0,0,0,0,0,0};
    for (int i = 0; i < deg; i += 8) {
        int idx = i + es;
        bool valid = idx < deg;
        int row = p0 + (valid ? idx : 0);
        const u16* hr = h + (long)row * 128 + cg * 16;
        short8 A = *(const short8*)(hr);
        short8 B = *(const short8*)(hr + 8);
#pragma unroll
        for (int j = 0; j < 4; j++) {
            float f  = fmaf(b2f((u16)A[2 * j]),     scf[j], shf[j]);
            float cc = fmaf(b2f((u16)A[2 * j + 1]), scc[j], shc[j]);
            float gg = gate(f, cc);
            acc[j] += valid ? gg : 0.f;
        }
#pragma unroll
        for (int j = 0; j < 4; j++) {
            float f  = fmaf(b2f((u16)B[2 * j]),     scf[4 + j], shf[4 + j]);
            float cc = fmaf(b2f((u16)B[2 * j + 1]), scc[4 + j], shc[4 + j]);
            float gg = gate(f, cc);
            acc[4 + j] += valid ? gg : 0.f;
        }
    }
#pragma unroll
    for (int m = 1; m < 8; m <<= 1)
#pragma unroll
        for (int j = 0; j < 8; j++) acc[j] += __shfl_xor(acc[j], m);
    if (es == 0) {
        float* sp = summed + (long)n * 64 + cg * 8;
        float4 v0 = {acc[0], acc[1], acc[2], acc[3]};
        float4 v1 = {acc[4], acc[5], acc[6], acc[7]};
        *(float4*)sp = v0;
        *(float4*)(sp + 4) = v1;
    }
}

// ---------------- t3/t2 gather (fallback, old h layout) ------------------------
__global__ __launch_bounds__(256) void k_scatter(
    const u16* __restrict__ h, const int* __restrict__ ptr,
    const int* __restrict__ cnt, const int* __restrict__ eidx,
    const float* __restrict__ sc, float* __restrict__ summed)
{
    int tid = threadIdx.x;
    int n = blockIdx.x * 4 + (tid >> 6);
    int l = tid & 63;
    int es = l & 7, cg = l >> 3;

    float4 a0 = *(const float4*)(sc + cg * 8);
    float4 a1 = *(const float4*)(sc + cg * 8 + 4);
    float4 b0 = *(const float4*)(sc + 128 + cg * 8);
    float4 b1 = *(const float4*)(sc + 128 + cg * 8 + 4);
    float4 c0 = *(const float4*)(sc + 64 + cg * 8);
    float4 c1 = *(const float4*)(sc + 64 + cg * 8 + 4);
    float4 d0 = *(const float4*)(sc + 192 + cg * 8);
    float4 d1 = *(const float4*)(sc + 192 + cg * 8 + 4);
    float scf[8] = {a0.x,a0.y,a0.z,a0.w,a1.x,a1.y,a1.z,a1.w};
    float shf[8] = {b0.x,b0.y,b0.z,b0.w,b1.x,b1.y,b1.z,b1.w};
    float scc[8] = {c0.x,c0.y,c0.z,c0.w,c1.x,c1.y,c1.z,c1.w};
    float shc[8] = {d0.x,d0.y,d0.z,d0.w,d1.x,d1.y,d1.z,d1.w};

    int p0 = ptr[n], deg = cnt[n];
    float acc[8] = {0,0,0,0,0,0,0,0};
    for (int i = 0; i < deg; i += 8) {
        int idx = i + es;
        bool valid = idx < deg;
        int e = eidx[p0 + (valid ? idx : 0)];
        const u16* hr = h + (long)e * 128;
        short8 f8 = *(const short8*)(hr + cg * 8);
        short8 c8 = *(const short8*)(hr + 64 + cg * 8);
#pragma unroll
        for (int j = 0; j < 8; j++) {
            float f  = fmaf(b2f((u16)f8[j]), scf[j], shf[j]);
            float cc = fmaf(b2f((u16)c8[j]), scc[j], shc[j]);
            float gg = gate(f, cc);
            acc[j] += valid ? gg : 0.f;
        }
    }
#pragma unroll
    for (int m = 1; m < 8; m <<= 1)
#pragma unroll
        for (int j = 0; j < 8; j++) acc[j] += __shfl_xor(acc[j], m);
    if (es == 0) {
        float* sp = summed + (long)n * 64 + cg * 8;
        float4 v0 = {acc[0], acc[1], acc[2], acc[3]};
        float4 v1 = {acc[4], acc[5], acc[6], acc[7]};
        *(float4*)sp = v0;
        *(float4*)(sp + 4) = v1;
    }
}

// ---------------- bn2 stats ----------------
__global__ __launch_bounds__(256) void k_bn2stats(const float* __restrict__ summed,
                                                  float* __restrict__ acc2)
{
    int tid = threadIdx.x; int c = tid & 63; int sub = tid >> 6;
    float s = 0.f, q = 0.f;
    for (int r = blockIdx.x * 4 + sub; r < NN; r += 4 * 128) {
        float v = summed[(long)r * 64 + c]; s += v; q = fmaf(v, v, q);
    }
    __shared__ float rs[256], rq[256];
    rs[tid] = s; rq[tid] = q; __syncthreads();
    if (tid < 64) {
        s = rs[tid] + rs[tid + 64] + rs[tid + 128] + rs[tid + 192];
        q = rq[tid] + rq[tid + 64] + rq[tid + 128] + rq[tid + 192];
        atomicAdd(&acc2[tid], s);
        atomicAdd(&acc2[64 + tid], q);
    }
}

// bn2 coefs + out_b init (fallback paths)
__global__ void k_bn2fin(const float* __restrict__ acc2,
                         const float* __restrict__ g, const float* __restrict__ b,
                         float* __restrict__ sc2, const float* __restrict__ outb,
                         float* __restrict__ out)
{
    int c = threadIdx.x;  // 256
    if (c < 64) {
        float mean = acc2[c] / (float)NN;
        float var = acc2[64 + c] / (float)NN - mean * mean;
        float scale = g[c] * rsqrtf(var + 1e-5f);
        sc2[c] = scale;
        sc2[64 + c] = b[c] - mean * scale;
    }
    out[(long)NN * 64 + c] = outb[0];
}

// ---------------- t4: atom_out + silu + logits + segmax, bn2 coefs per block ---
__global__ __launch_bounds__(256) void k_nodepost2(
    const float* __restrict__ summed, const float* __restrict__ acc2,
    const float* __restrict__ g, const float* __restrict__ b,
    const float* __restrict__ attW, const float* __restrict__ attb,
    const int* __restrict__ batch, float* __restrict__ out,
    float* __restrict__ elog, unsigned* __restrict__ segmax)
{
    __shared__ float ssc2[128];
    int tid = threadIdx.x;
    if (tid < 64) {                        // identical to k_bn2fin
        float mean = acc2[tid] / (float)NN;
        float var = acc2[64 + tid] / (float)NN - mean * mean;
        float scale = g[tid] * rsqrtf(var + 1e-5f);
        ssc2[tid] = scale;
        ssc2[64 + tid] = b[tid] - mean * scale;
    }
    __syncthreads();

    int n = blockIdx.x * 4 + (tid >> 6); int c = tid & 63;
    float v = summed[(long)n * 64 + c];
    float ao = fmaf(v, ssc2[c], ssc2[64 + c]);
    out[(long)n * 64 + c] = ao;
    float h = fsilu(ao);
    float p = h * attW[c];
#pragma unroll
    for (int off = 32; off; off >>= 1) p += __shfl_down(p, off, 64);
    if (c == 0) {
        float logit = p + attb[0];
        elog[n] = logit;
        unsigned u = __float_as_uint(logit);
        u = (u & 0x80000000u) ? ~u : (u | 0x80000000u);
        atomicMax(&segmax[batch[n]], u);
    }
}

// fallback nodepost
__global__ __launch_bounds__(256) void k_nodepost(
    const float* __restrict__ summed, const float* __restrict__ sc2,
    const float* __restrict__ attW, const float* __restrict__ attb,
    const int* __restrict__ batch, float* __restrict__ out,
    float* __restrict__ elog, unsigned* __restrict__ segmax)
{
    int tid = threadIdx.x; int n = blockIdx.x * 4 + (tid >> 6); int c = tid & 63;
    float v = summed[(long)n * 64 + c];
    float ao = fmaf(v, sc2[c], sc2[64 + c]);
    out[(long)n * 64 + c] = ao;
    float h = fsilu(ao);
    float p = h * attW[c];
#pragma unroll
    for (int off = 32; off; off >>= 1) p += __shfl_down(p, off, 64);
    if (c == 0) {
        float logit = p + attb[0];
        elog[n] = logit;
        unsigned u = __float_as_uint(logit);
        u = (u & 0x80000000u) ? ~u : (u | 0x80000000u);
        atomicMax(&segmax[batch[n]], u);
    }
}

// t4: denom + crys out_b init
__global__ void k_denom2(const int* __restrict__ batch,
                         const unsigned* __restrict__ segmax,
                         float* __restrict__ elog, float* __restrict__ denom,
                         const float* __restrict__ outb, float* __restrict__ out)
{
    int n = blockIdx.x * 256 + threadIdx.x;
    if (n < NG) out[(long)NN * 64 + n] = outb[0];
    if (n >= NN) return;
    int b = batch[n];
    unsigned u = segmax[b];
    u = (u & 0x80000000u) ? (u & 0x7FFFFFFFu) : ~u;
    float e = __expf(elog[n] - __uint_as_float(u));
    elog[n] = e;
    atomicAdd(&denom[b], e);
}

__global__ void k_denom(const int* __restrict__ batch,
                        const unsigned* __restrict__ segmax,
                        float* __restrict__ elog, float* __restrict__ denom)
{
    int n = blockIdx.x * 256 + threadIdx.x;
    if (n >= NN) return;
    int b = batch[n];
    unsigned u = segmax[b];
    u = (u & 0x80000000u) ? (u & 0x7FFFFFFFu) : ~u;
    float e = __expf(elog[n] - __uint_as_float(u));
    elog[n] = e;
    atomicAdd(&denom[b], e);
}

// weighted pooling fused with out_W projection
__global__ __launch_bounds__(256) void k_crys(
    const float* __restrict__ atom_out, const float* __restrict__ elog,
    const float* __restrict__ denom, const int* __restrict__ batch,
    const float* __restrict__ outW, float* __restrict__ out)
{
    int tid = threadIdx.x; int n = blockIdx.x * 4 + (tid >> 6); int l = tid & 63;
    int b = batch[n];
    float alpha = elog[n] / denom[b];
    float ao = atom_out[(long)n * 64 + l];
    float p = fsilu(ao) * outW[l];
#pragma unroll
    for (int off = 32; off; off >>= 1) p += __shfl_down(p, off, 64);
    if (l == 0) atomicAdd(&out[(long)NN * 64 + b], alpha * p);
}

extern "C" void kernel_launch(void* const* d_in, const int* in_sizes, int n_in,
                              void* d_out, int out_size, void* d_ws, size_t ws_size,
                              hipStream_t stream)
{
    const float* x    = (const float*)d_in[0];
    const float* eatt = (const float*)d_in[1];
    const float* lf   = (const float*)d_in[2];
    const int*   ei   = (const int*)d_in[3];
    const int*   batch= (const int*)d_in[4];
    const float* embW = (const float*)d_in[5];
    const float* embB = (const float*)d_in[6];
    const float* fcW  = (const float*)d_in[7];
    // d_in[8] fc_b folds into bn1 shift
    const float* bn1g = (const float*)d_in[9];
    const float* bn1b = (const float*)d_in[10];
    const float* bn2g = (const float*)d_in[11];
    const float* bn2b = (const float*)d_in[12];
    const float* attW = (const float*)d_in[13];
    const float* attB = (const float*)d_in[14];
    const float* outW = (const float*)d_in[15];
    const float* outB = (const float*)d_in[16];
    float* out = (float*)d_out;
    float* ws  = (float*)d_ws;

    u16* afb  = (u16*)(ws + OFF_AFB);
    u16* wT   = (u16*)(ws + OFF_WT);
    int* cnt  = (int*)(ws + OFF_CNT);
    int* ptr  = (int*)(ws + OFF_PTR);
    int* head = (int*)(ws + OFF_HEAD);
    int* bsum = (int*)(ws + OFF_BSUM);
    int* bofs = (int*)(ws + OFF_BOFS);
    int* eidx = (int*)(ws + OFF_EIDX);
    u16* h    = (u16*)(ws + OFF_H);

    const bool t4 = ws_size >= (size_t)OFF_T4_END * sizeof(float);
    const bool t3 = ws_size >= (size_t)OFF_T3_END * sizeof(float);
    const bool t2 = ws_size >= (size_t)OFF_T2_END * sizeof(float);

    if (t4) {
        u16* wT3  = wT;
        u16* wP   = wT + 8192;
        float* P1 = ws + OFF_P;
        u16* P2   = (u16*)(ws + OFF_P2);
        int* srcC = (int*)(ws + OFF_SRCC);
        int* dstC = (int*)(ws + OFF_DSTC);
        u16* eaB  = (u16*)(ws + OFF_EAB);
        k_embed2<<<12500, 256, 0, stream>>>(x, lf, embW, embB, afb, fcW, wT3, wP, ws);
        k_hist2<<<(NE * 6 + 255) / 256, 256, 0, stream>>>(ei, eatt, cnt, eaB);
        k_partial<<<(NN + SCAN_B - 1) / SCAN_B, SCAN_B, 0, stream>>>(cnt, ptr, bsum);
        k_scanb<<<1, 256, 0, stream>>>(bsum, bofs, (NN + SCAN_B - 1) / SCAN_B);
        k_addofs<<<(NN + 255) / 256, 256, 0, stream>>>(ptr, bofs, head);
        k_fill2<<<(NE + 255) / 256, 256, 0, stream>>>(ei, head, eidx, srcC, dstC);
        k_pnodeS<<<(NN + 63) / 64, 256, 0, stream>>>(afb, wP, P1, P2);
        k_gemm_h6<<<NE / 64, 256, 0, stream>>>(eaB, eidx, srcC, dstC, wT3, P1, P2, h,
                                               ws + OFF_BN1SPR);
        k_scatter4<<<NN / 4, 256, 0, stream>>>(h, ptr, cnt, ws + OFF_BN1SPR,
                                               bn1g, bn1b, ws + OFF_SUMMED);
        k_bn2stats<<<128, 256, 0, stream>>>(ws + OFF_SUMMED, ws + OFF_BN2ACC);
        k_nodepost2<<<12500, 256, 0, stream>>>(ws + OFF_SUMMED, ws + OFF_BN2ACC,
                                               bn2g, bn2b, attW, attB, batch, out,
                                               ws + OFF_ELOG,
                                               (unsigned*)(ws + OFF_SEGMAX));
        k_denom2<<<196, 256, 0, stream>>>(batch, (const unsigned*)(ws + OFF_SEGMAX),
                                          ws + OFF_ELOG, ws + OFF_DENOM, outB, out);
        k_crys<<<12500, 256, 0, stream>>>(out, ws + OFF_ELOG, ws + OFF_DENOM, batch,
                                          outW, out);
        return;
    }

    k_embed<<<12500, 256, 0, stream>>>(x, lf, embW, embB, afb);

    if (t3) {
        u16* wT3 = wT;
        u16* wP  = wT + 8192;
        float* P = ws + OFF_P;
        k_prepw2<<<96, 256, 0, stream>>>(fcW, wT3, wP);
        hipMemsetAsync(ws + OFF_BN1SPR, 0,
                       (size_t)(OFF_PTR - OFF_BN1SPR) * sizeof(float), stream);
        k_hist<<<(NE + 255) / 256, 256, 0, stream>>>(ei, cnt);
        k_partial<<<(NN + SCAN_B - 1) / SCAN_B, SCAN_B, 0, stream>>>(cnt, ptr, bsum);
        k_scanb<<<1, 256, 0, stream>>>(bsum, bofs, (NN + SCAN_B - 1) / SCAN_B);
        k_addofs<<<(NN + 255) / 256, 256, 0, stream>>>(ptr, bofs, head);
        k_fill<<<(NE + 255) / 256, 256, 0, stream>>>(ei, head, eidx);
        k_pnode<<<(NN + 63) / 64, 256, 0, stream>>>(afb, wP, P);
        k_gemm_h2<<<NE / 64, 256, 0, stream>>>(eatt, ei, wT3, P, h, ws + OFF_BN1SPR);
        k_bn1fin<<<1, 128, 0, stream>>>(ws + OFF_BN1SPR, bn1g, bn1b, ws + OFF_BN1SC);
        k_scatter<<<NN / 4, 256, 0, stream>>>(h, ptr, cnt, eidx, ws + OFF_BN1SC,
                                              ws + OFF_SUMMED);
    } else if (t2) {
        k_prepw<<<96, 256, 0, stream>>>(fcW, wT);
        hipMemsetAsync(ws + OFF_BN1SPR, 0,
                       (size_t)(OFF_PTR - OFF_BN1SPR) * sizeof(float), stream);
        k_hist<<<(NE + 255) / 256, 256, 0, stream>>>(ei, cnt);
        k_partial<<<(NN + SCAN_B - 1) / SCAN_B, SCAN_B, 0, stream>>>(cnt, ptr, bsum);
        k_scanb<<<1, 256, 0, stream>>>(bsum, bofs, (NN + SCAN_B - 1) / SCAN_B);
        k_addofs<<<(NN + 255) / 256, 256, 0, stream>>>(ptr, bofs, head);
        k_fill<<<(NE + 255) / 256, 256, 0, stream>>>(ei, head, eidx);
        k_gemm_h<<<NE / 64, 256, 0, stream>>>(afb, eatt, ei, wT, h, ws + OFF_BN1SPR);
        k_bn1fin<<<1, 128, 0, stream>>>(ws + OFF_BN1SPR, bn1g, bn1b, ws + OFF_BN1SC);
        k_scatter<<<NN / 4, 256, 0, stream>>>(h, ptr, cnt, eidx, ws + OFF_BN1SC,
                                              ws + OFF_SUMMED);
    } else {
        k_prepw<<<96, 256, 0, stream>>>(fcW, wT);
        hipMemsetAsync(ws + OFF_SUMMED, 0,
                       (size_t)(OFF_PTR - OFF_SUMMED) * sizeof(float), stream);
        k_gemm<0><<<NE / 64, 256, 0, stream>>>(afb, eatt, ei, wT, ws + OFF_BN1SC,
                                               ws + OFF_BN1SPR);
        k_bn1fin<<<1, 128, 0, stream>>>(ws + OFF_BN1SPR, bn1g, bn1b, ws + OFF_BN1SC);
        k_gemm<1><<<NE / 64, 256, 0, stream>>>(afb, eatt, ei, wT, ws + OFF_BN1SC,
                                               ws + OFF_SUMMED);
    }

    k_bn2stats<<<128, 256, 0, stream>>>(ws + OFF_SUMMED, ws + OFF_BN2ACC);
    k_bn2fin<<<1, 256, 0, stream>>>(ws + OFF_BN2ACC, bn2g, bn2b, ws + OFF_BN2SC,
                                    outB, out);
    k_nodepost<<<12500, 256, 0, stream>>>(ws + OFF_SUMMED, ws + OFF_BN2SC, attW, attB,
                                          batch, out, ws + OFF_ELOG,
                                          (unsigned*)(ws + OFF_SEGMAX));
    k_denom<<<196, 256, 0, stream>>>(batch, (const unsigned*)(ws + OFF_SEGMAX),
                                     ws + OFF_ELOG, ws + OFF_DENOM);
    k_crys<<<12500, 256, 0, stream>>>(out, ws + OFF_ELOG, ws + OFF_DENOM, batch,
                                      outW, out);
}